// Round 1
// baseline (688.894 us; speedup 1.0000x reference)
//
#include <hip/hip_runtime.h>
#include <hip/hip_bf16.h>
#include <math.h>

// ---------------------------------------------------------------------------
// FlaxLTX2AudioAttnBlock: GN -> QKV proj -> softmax(QK^T/sqrt(C)) V -> proj -> +x
// B=4, H=W=64 (N=4096 tokens/batch), C=512, G=32 groups.
// Strategy: bf16 MFMA GEMMs (fp32 accum), non-flash attention with fp32 S.
// ---------------------------------------------------------------------------

typedef __bf16 bf16;
typedef float f32x4 __attribute__((ext_vector_type(4)));
typedef __bf16 bf16x8 __attribute__((ext_vector_type(8)));
typedef __bf16 bf16x4 __attribute__((ext_vector_type(4)));

#define AS1 __attribute__((address_space(1)))
#define AS3 __attribute__((address_space(3)))

#define NB   4
#define NTOK 4096
#define CCH  512
#define NGRP 32

__device__ __forceinline__ void gload_lds16(const void* g, void* l) {
  __builtin_amdgcn_global_load_lds((AS1 void*)(g), (AS3 void*)(l), 16, 0, 0);
}

// ---------------- GroupNorm stats: one block per (b,g) ----------------------
__global__ __launch_bounds__(256) void gn_stats(const float* __restrict__ x,
                                                float* __restrict__ stats) {
  const int bg = blockIdx.x;           // 0..127
  const int b = bg >> 5, g = bg & 31;
  const float* xb = x + (size_t)b * NTOK * CCH + g * 16;
  float s = 0.f, ss = 0.f;
  for (int i = threadIdx.x; i < NTOK * 16; i += 256) {
    const int pos = i >> 4, c = i & 15;
    const float v = xb[(size_t)pos * CCH + c];
    s += v; ss += v * v;
  }
  const int lane = threadIdx.x & 63, wave = threadIdx.x >> 6;
  #pragma unroll
  for (int off = 32; off > 0; off >>= 1) {
    s  += __shfl_down(s, off);
    ss += __shfl_down(ss, off);
  }
  __shared__ float rs[4], rss[4];
  if (lane == 0) { rs[wave] = s; rss[wave] = ss; }
  __syncthreads();
  if (threadIdx.x == 0) {
    const float S0 = rs[0] + rs[1] + rs[2] + rs[3];
    const float SS = rss[0] + rss[1] + rss[2] + rss[3];
    const float inv = 1.f / (NTOK * 16.f);
    const float mean = S0 * inv;
    const float var = SS * inv - mean * mean;
    stats[bg * 2]     = mean;
    stats[bg * 2 + 1] = rsqrtf(var + 1e-6f);
  }
}

// ---------------- normalize + affine + cast to bf16 -------------------------
__global__ __launch_bounds__(256) void gn_apply(const float4* __restrict__ x4,
                                                const float* __restrict__ stats,
                                                const float* __restrict__ gsc,
                                                const float* __restrict__ gbi,
                                                bf16* __restrict__ hf) {
  const int i = blockIdx.x * 256 + threadIdx.x;   // over 2,097,152 float4s
  const float4 v = x4[i];
  const size_t e = (size_t)i * 4;
  const int c = (int)(e & (CCH - 1));
  const int b = (int)(e >> 21);                   // 4096*512 = 2^21 per batch
  const int g = c >> 4;
  const float mean = stats[(b * NGRP + g) * 2];
  const float rstd = stats[(b * NGRP + g) * 2 + 1];
  bf16x4 o;
  o[0] = (bf16)((v.x - mean) * rstd * gsc[c + 0] + gbi[c + 0]);
  o[1] = (bf16)((v.y - mean) * rstd * gsc[c + 1] + gbi[c + 1]);
  o[2] = (bf16)((v.z - mean) * rstd * gsc[c + 2] + gbi[c + 2]);
  o[3] = (bf16)((v.w - mean) * rstd * gsc[c + 3] + gbi[c + 3]);
  *reinterpret_cast<bf16x4*>(&hf[e]) = o;
}

// ---------------- weight transpose+cast: w[k][n] f32 -> wT[n][k] bf16 -------
__global__ __launch_bounds__(256) void wcast_t(const float* __restrict__ wq,
                                               const float* __restrict__ wk,
                                               const float* __restrict__ wv,
                                               const float* __restrict__ wo,
                                               bf16* __restrict__ dst) {
  const int w = blockIdx.y;
  const float* src = (w == 0) ? wq : (w == 1) ? wk : (w == 2) ? wv : wo;
  bf16* out = dst + (size_t)w * CCH * CCH;
  const int t = blockIdx.x;                // 8x8 tiles of 64x64
  const int tr = t >> 3, tc = t & 7;
  __shared__ float tile[64][65];
  for (int i = threadIdx.x; i < 4096; i += 256) {
    const int r = i >> 6, c = i & 63;
    tile[r][c] = src[(size_t)(tr * 64 + r) * CCH + tc * 64 + c];
  }
  __syncthreads();
  for (int i = threadIdx.x; i < 4096; i += 256) {
    const int r = i >> 6, c = i & 63;
    out[(size_t)(tc * 64 + r) * CCH + tr * 64 + c] = (bf16)tile[c][r];
  }
}

// ---------------- bf16 transpose: v[tok][d] -> vt[d][tok] per batch ---------
__global__ __launch_bounds__(256) void vtrans(const bf16* __restrict__ v,
                                              bf16* __restrict__ vt) {
  const int b = blockIdx.y;
  const bf16* src = v + (size_t)b * NTOK * CCH;
  bf16* out = vt + (size_t)b * CCH * NTOK;
  const int t = blockIdx.x;                // (4096/64)x(512/64) = 64x8 tiles
  const int tr = t >> 3, tc = t & 7;
  __shared__ bf16 tile[64][65];
  for (int i = threadIdx.x; i < 4096; i += 256) {
    const int r = i >> 6, c = i & 63;
    tile[r][c] = src[(size_t)(tr * 64 + r) * CCH + tc * 64 + c];
  }
  __syncthreads();
  for (int i = threadIdx.x; i < 4096; i += 256) {
    const int r = i >> 6, c = i & 63;
    out[(size_t)(tc * 64 + r) * NTOK + tr * 64 + c] = tile[c][r];
  }
}

// ---------------- row softmax: S f32 [4096][4096] -> P bf16 -----------------
__global__ __launch_bounds__(256) void softmax_rows(const float* __restrict__ S,
                                                    bf16* __restrict__ P) {
  const int row = blockIdx.x;
  const float4* s4 = reinterpret_cast<const float4*>(S + (size_t)row * NTOK);
  const int tid = threadIdx.x, lane = tid & 63, wave = tid >> 6;
  float v[16];
  float m = -1e30f;
  #pragma unroll
  for (int t = 0; t < 4; ++t) {
    const float4 q = s4[t * 256 + tid];
    v[t*4+0] = q.x; v[t*4+1] = q.y; v[t*4+2] = q.z; v[t*4+3] = q.w;
    m = fmaxf(m, fmaxf(fmaxf(q.x, q.y), fmaxf(q.z, q.w)));
  }
  #pragma unroll
  for (int off = 32; off > 0; off >>= 1) m = fmaxf(m, __shfl_xor(m, off));
  __shared__ float redm[4], redsum[4];
  if (lane == 0) redm[wave] = m;
  __syncthreads();
  m = fmaxf(fmaxf(redm[0], redm[1]), fmaxf(redm[2], redm[3]));
  float sum = 0.f;
  #pragma unroll
  for (int i = 0; i < 16; ++i) { v[i] = __expf(v[i] - m); sum += v[i]; }
  #pragma unroll
  for (int off = 32; off > 0; off >>= 1) sum += __shfl_xor(sum, off);
  if (lane == 0) redsum[wave] = sum;
  __syncthreads();
  sum = redsum[0] + redsum[1] + redsum[2] + redsum[3];
  const float r = 1.f / sum;
  bf16* p = P + (size_t)row * NTOK;
  #pragma unroll
  for (int t = 0; t < 4; ++t) {
    bf16x4 o;
    o[0] = (bf16)(v[t*4+0] * r); o[1] = (bf16)(v[t*4+1] * r);
    o[2] = (bf16)(v[t*4+2] * r); o[3] = (bf16)(v[t*4+3] * r);
    *reinterpret_cast<bf16x4*>(&p[(size_t)(t * 256 + tid) * 4]) = o;
  }
}

// ---------------- MFMA GEMM: C[M][N] = A[M][K] @ Bt[N][K]^T (+ epilogue) ----
// EPI: 0 = bias, bf16 out | 1 = *scale, f32 out | 2 = plain bf16 out
//      3 = bias + residual, f32 out
template <int BMt, int BNt, int EPI>
__global__ __launch_bounds__(256) void gemm_bt(
    const bf16* __restrict__ A, const bf16* __restrict__ Bt,
    void* __restrict__ C, const float* __restrict__ bias,
    const float* __restrict__ resid, int M, int N, int K, float scale) {
  constexpr int BK = 64;
  __shared__ bf16 Al[BMt * BK];
  __shared__ bf16 Bl[BNt * BK];
  const int tid = threadIdx.x;
  const int lane = tid & 63;
  const int wave = tid >> 6;
  const int fr = lane & 15;     // frag row (A:m / B:n / C:col)
  const int fq = lane >> 4;     // frag quad (k-group; C: row-group)
  const int nbn = N / BNt;
  const int bm = blockIdx.x / nbn, bn = blockIdx.x % nbn;
  const int wr = wave >> 1, wc = wave & 1;       // 2x2 wave grid
  constexpr int MF = BMt / 32;  // 16-frags per wave in M
  constexpr int NF = BNt / 32;
  constexpr int AIT = (BMt * BK) / (8 * 256);    // 16B-chunk issues per thread
  constexpr int BIT = (BNt * BK) / (8 * 256);

  f32x4 acc[MF][NF];
  #pragma unroll
  for (int m2 = 0; m2 < MF; ++m2)
    #pragma unroll
    for (int n2 = 0; n2 < NF; ++n2)
      acc[m2][n2] = f32x4{0.f, 0.f, 0.f, 0.f};

  for (int kt = 0; kt < K; kt += BK) {
    #pragma unroll
    for (int i = 0; i < AIT; ++i) {
      const int c = i * 256 + wave * 64 + lane;
      const int r = c >> 3, col = c & 7;        // row, 16B-chunk within row
      gload_lds16(A + (size_t)(bm * BMt + r) * K + kt + col * 8,
                  Al + (size_t)(i * 256 + wave * 64) * 8);
    }
    #pragma unroll
    for (int i = 0; i < BIT; ++i) {
      const int c = i * 256 + wave * 64 + lane;
      const int r = c >> 3, col = c & 7;
      gload_lds16(Bt + (size_t)(bn * BNt + r) * K + kt + col * 8,
                  Bl + (size_t)(i * 256 + wave * 64) * 8);
    }
    __syncthreads();
    #pragma unroll
    for (int kk = 0; kk < BK; kk += 32) {
      bf16x8 af[MF], bfg[NF];
      #pragma unroll
      for (int m2 = 0; m2 < MF; ++m2)
        af[m2] = *reinterpret_cast<const bf16x8*>(
            &Al[(size_t)(wr * (BMt / 2) + m2 * 16 + fr) * BK + kk + fq * 8]);
      #pragma unroll
      for (int n2 = 0; n2 < NF; ++n2)
        bfg[n2] = *reinterpret_cast<const bf16x8*>(
            &Bl[(size_t)(wc * (BNt / 2) + n2 * 16 + fr) * BK + kk + fq * 8]);
      #pragma unroll
      for (int m2 = 0; m2 < MF; ++m2)
        #pragma unroll
        for (int n2 = 0; n2 < NF; ++n2)
          acc[m2][n2] = __builtin_amdgcn_mfma_f32_16x16x32_bf16(
              af[m2], bfg[n2], acc[m2][n2], 0, 0, 0);
    }
    __syncthreads();
  }

  #pragma unroll
  for (int m2 = 0; m2 < MF; ++m2) {
    #pragma unroll
    for (int n2 = 0; n2 < NF; ++n2) {
      #pragma unroll
      for (int j = 0; j < 4; ++j) {
        const int row = bm * BMt + wr * (BMt / 2) + m2 * 16 + fq * 4 + j;
        const int col = bn * BNt + wc * (BNt / 2) + n2 * 16 + fr;
        const float val = acc[m2][n2][j];
        const size_t idx = (size_t)row * N + col;
        if constexpr (EPI == 0) {
          ((bf16*)C)[idx] = (bf16)(val + bias[col]);
        } else if constexpr (EPI == 1) {
          ((float*)C)[idx] = val * scale;
        } else if constexpr (EPI == 2) {
          ((bf16*)C)[idx] = (bf16)val;
        } else {
          ((float*)C)[idx] = val + bias[col] + resid[idx];
        }
      }
    }
  }
}

// ---------------------------------------------------------------------------
extern "C" void kernel_launch(void* const* d_in, const int* in_sizes, int n_in,
                              void* d_out, int out_size, void* d_ws, size_t ws_size,
                              hipStream_t stream) {
  const float* x   = (const float*)d_in[0];
  const float* gsc = (const float*)d_in[1];
  const float* gbi = (const float*)d_in[2];
  const float* wq  = (const float*)d_in[3];
  const float* bq  = (const float*)d_in[4];
  const float* wk  = (const float*)d_in[5];
  const float* bk  = (const float*)d_in[6];
  const float* wv  = (const float*)d_in[7];
  const float* bv  = (const float*)d_in[8];
  const float* wo  = (const float*)d_in[9];
  const float* bo  = (const float*)d_in[10];
  float* out = (float*)d_out;
  char* ws = (char*)d_ws;

  // ws layout (bytes); P aliases hf (dead before P written), v aliases S.
  bf16*  P     = (bf16*)(ws + 0);            // 4096*4096*2  = 33,554,432
  bf16*  hf    = (bf16*)(ws + 0);            // 16384*512*2  (sub-region of P)
  bf16*  wT    = (bf16*)(ws + 33554432);     // 4*512*512*2  =  2,097,152
  bf16*  q     = (bf16*)(ws + 35651584);     // 16,777,216
  bf16*  k     = (bf16*)(ws + 52428800);     // 16,777,216
  bf16*  vt    = (bf16*)(ws + 69206016);     // 16,777,216
  bf16*  o     = (bf16*)(ws + 85983232);     // 16,777,216
  float* S     = (float*)(ws + 102760448);   // 4096*4096*4  = 67,108,864
  bf16*  vtmp  = (bf16*)(ws + 102760448);    // aliases S (dead before S written)
  float* stats = (float*)(ws + 169869312);   // 128*2*4

  gn_stats<<<NB * NGRP, 256, 0, stream>>>(x, stats);
  gn_apply<<<8192, 256, 0, stream>>>((const float4*)x, stats, gsc, gbi, hf);
  wcast_t<<<dim3(64, 4), 256, 0, stream>>>(wq, wk, wv, wo, wT);

  // QKV projections: M=16384, N=512, K=512
  gemm_bt<128, 128, 0><<<512, 256, 0, stream>>>(hf, wT,            q,    bq, nullptr, 16384, 512, 512, 0.f);
  gemm_bt<128, 128, 0><<<512, 256, 0, stream>>>(hf, wT + 262144,   k,    bk, nullptr, 16384, 512, 512, 0.f);
  gemm_bt<128, 128, 0><<<512, 256, 0, stream>>>(hf, wT + 524288,   vtmp, bv, nullptr, 16384, 512, 512, 0.f);
  vtrans<<<dim3(512, 4), 256, 0, stream>>>(vtmp, vt);

  const float sscale = 0.044194173824159216f;  // 1/sqrt(512)
  for (int b = 0; b < NB; ++b) {
    const size_t tb = (size_t)b * NTOK * CCH;
    // S = (q_b @ k_b^T) * scale : M=N=4096, K=512
    gemm_bt<128, 128, 1><<<1024, 256, 0, stream>>>(q + tb, k + tb, S, nullptr, nullptr, NTOK, NTOK, CCH, sscale);
    softmax_rows<<<NTOK, 256, 0, stream>>>(S, P);
    // o_b = P @ V : M=4096, N=512, K=4096 ; BN=64 -> 256 blocks (fill CUs)
    gemm_bt<128, 64, 2><<<256, 256, 0, stream>>>(P, vt + tb, o + tb, nullptr, nullptr, NTOK, CCH, NTOK, 0.f);
  }
  // out = x + o @ wo + bo : M=16384, N=512, K=512
  gemm_bt<128, 128, 3><<<512, 256, 0, stream>>>(o, wT + 786432, out, bo, x, 16384, 512, 512, 0.f);
}

// Round 2
// 416.065 us; speedup vs baseline: 1.6557x; 1.6557x over previous
//
#include <hip/hip_runtime.h>
#include <hip/hip_bf16.h>
#include <math.h>

// ---------------------------------------------------------------------------
// FlaxLTX2AudioAttnBlock: GN -> QKV proj -> softmax(QK^T/sqrt(C)) V -> proj -> +x
// B=4, N=4096 tokens/batch, C=512, G=32 groups.
// R2: two-stage GroupNorm stats; fused QKV GEMM (N=1536, scale folded into Q);
//     bf16 scores with in-place softmax; batched QK/softmax/PV launches.
// ---------------------------------------------------------------------------

typedef __bf16 bf16;
typedef float f32x4 __attribute__((ext_vector_type(4)));
typedef __bf16 bf16x8 __attribute__((ext_vector_type(8)));
typedef __bf16 bf16x4 __attribute__((ext_vector_type(4)));

#define AS1 __attribute__((address_space(1)))
#define AS3 __attribute__((address_space(3)))

#define NB   4
#define NTOK 4096
#define CCH  512
#define NGRP 32

__device__ __forceinline__ void gload_lds16(const void* g, void* l) {
  __builtin_amdgcn_global_load_lds((AS1 void*)(g), (AS3 void*)(l), 16, 0, 0);
}

// ---------------- GroupNorm stage 1: partial sums ---------------------------
// grid (64 chunks, 4 batches), 256 threads. Each block: 64 rows x 512 ch,
// fully coalesced float4 reads; each thread owns a fixed 4-channel column.
__global__ __launch_bounds__(256) void gn_partial(const float4* __restrict__ x4,
                                                  float* __restrict__ partials) {
  const int chunk = blockIdx.x, b = blockIdx.y;
  const int tid = threadIdx.x;
  const size_t base = ((size_t)b * NTOK + (size_t)chunk * 64) * 128;  // float4s
  float s = 0.f, ss = 0.f;
  #pragma unroll 4
  for (int it = 0; it < 32; ++it) {
    const float4 v = x4[base + it * 256 + tid];
    s  += v.x + v.y + v.z + v.w;
    ss += v.x * v.x + v.y * v.y + v.z * v.z + v.w * v.w;
  }
  __shared__ float ls[256], lss[256];
  ls[tid] = s; lss[tid] = ss;
  __syncthreads();
  if (tid < 32) {
    float ps = 0.f, pss = 0.f;
    #pragma unroll
    for (int j = 0; j < 4; ++j) {
      ps  += ls[tid * 4 + j] + ls[128 + tid * 4 + j];
      pss += lss[tid * 4 + j] + lss[128 + tid * 4 + j];
    }
    const size_t o = (((size_t)b * 64 + chunk) * 32 + tid) * 2;
    partials[o] = ps; partials[o + 1] = pss;
  }
}

// ---------------- GroupNorm stage 2: reduce 64 chunks -> stats --------------
__global__ __launch_bounds__(128) void gn_reduce(const float* __restrict__ partials,
                                                 float* __restrict__ stats) {
  const int tid = threadIdx.x;          // tid = b*32 + g
  const int b = tid >> 5, g = tid & 31;
  float s = 0.f, ss = 0.f;
  for (int c = 0; c < 64; ++c) {
    const size_t o = (((size_t)b * 64 + c) * 32 + g) * 2;
    s += partials[o]; ss += partials[o + 1];
  }
  const float inv = 1.f / (NTOK * 16.f);
  const float mean = s * inv;
  const float var = ss * inv - mean * mean;
  stats[tid * 2] = mean;
  stats[tid * 2 + 1] = rsqrtf(var + 1e-6f);
}

// ---------------- normalize + affine + cast to bf16 -------------------------
__global__ __launch_bounds__(256) void gn_apply(const float4* __restrict__ x4,
                                                const float* __restrict__ stats,
                                                const float* __restrict__ gsc,
                                                const float* __restrict__ gbi,
                                                bf16* __restrict__ hf) {
  const int i = blockIdx.x * 256 + threadIdx.x;   // over 2,097,152 float4s
  const float4 v = x4[i];
  const size_t e = (size_t)i * 4;
  const int c = (int)(e & (CCH - 1));
  const int b = (int)(e >> 21);
  const int g = c >> 4;
  const float mean = stats[(b * NGRP + g) * 2];
  const float rstd = stats[(b * NGRP + g) * 2 + 1];
  bf16x4 o;
  o[0] = (bf16)((v.x - mean) * rstd * gsc[c + 0] + gbi[c + 0]);
  o[1] = (bf16)((v.y - mean) * rstd * gsc[c + 1] + gbi[c + 1]);
  o[2] = (bf16)((v.z - mean) * rstd * gsc[c + 2] + gbi[c + 2]);
  o[3] = (bf16)((v.w - mean) * rstd * gsc[c + 3] + gbi[c + 3]);
  *reinterpret_cast<bf16x4*>(&hf[e]) = o;
}

// ---------------- weight transpose+cast + bias concat -----------------------
__global__ __launch_bounds__(256) void wcast_t(const float* __restrict__ wq,
                                               const float* __restrict__ wk,
                                               const float* __restrict__ wv,
                                               const float* __restrict__ wo,
                                               const float* __restrict__ bq,
                                               const float* __restrict__ bk,
                                               const float* __restrict__ bv,
                                               bf16* __restrict__ dst,
                                               float* __restrict__ bcat) {
  const int w = blockIdx.y;
  const float* src = (w == 0) ? wq : (w == 1) ? wk : (w == 2) ? wv : wo;
  bf16* out = dst + (size_t)w * CCH * CCH;
  const int t = blockIdx.x;                // 8x8 tiles of 64x64
  const int tr = t >> 3, tc = t & 7;
  if (t == 0 && w < 3) {
    const float* bsrc = (w == 0) ? bq : (w == 1) ? bk : bv;
    for (int i = threadIdx.x; i < CCH; i += 256) bcat[w * CCH + i] = bsrc[i];
  }
  __shared__ float tile[64][65];
  for (int i = threadIdx.x; i < 4096; i += 256) {
    const int r = i >> 6, c = i & 63;
    tile[r][c] = src[(size_t)(tr * 64 + r) * CCH + tc * 64 + c];
  }
  __syncthreads();
  for (int i = threadIdx.x; i < 4096; i += 256) {
    const int r = i >> 6, c = i & 63;
    out[(size_t)(tc * 64 + r) * CCH + tr * 64 + c] = (bf16)tile[c][r];
  }
}

// ---------------- bf16 transpose: qkv v-cols [tok][1536] -> vt[d][tok] ------
__global__ __launch_bounds__(256) void vtrans(const bf16* __restrict__ qkv,
                                              bf16* __restrict__ vt) {
  const int b = blockIdx.y;
  const bf16* src = qkv + (size_t)b * NTOK * 1536 + 1024;   // v columns
  bf16* out = vt + (size_t)b * CCH * NTOK;
  const int t = blockIdx.x;                // 64x8 tiles of 64x64
  const int tr = t >> 3, tc = t & 7;
  __shared__ bf16 tile[64][65];
  for (int i = threadIdx.x; i < 4096; i += 256) {
    const int r = i >> 6, c = i & 63;
    tile[r][c] = src[(size_t)(tr * 64 + r) * 1536 + tc * 64 + c];
  }
  __syncthreads();
  for (int i = threadIdx.x; i < 4096; i += 256) {
    const int r = i >> 6, c = i & 63;
    out[(size_t)(tc * 64 + r) * NTOK + tr * 64 + c] = tile[c][r];
  }
}

// ---------------- row softmax, bf16 in-place --------------------------------
__global__ __launch_bounds__(256) void softmax_rows_bf16(bf16* __restrict__ Sall) {
  const size_t row = (size_t)blockIdx.y * NTOK + blockIdx.x;
  bf16* p = Sall + row * NTOK;
  const int tid = threadIdx.x, lane = tid & 63, wave = tid >> 6;
  const bf16x8 a = ((const bf16x8*)p)[tid];
  const bf16x8 b2 = ((const bf16x8*)p)[256 + tid];
  float v[16];
  float m = -1e30f;
  #pragma unroll
  for (int j = 0; j < 8; ++j) { v[j] = (float)a[j]; v[8 + j] = (float)b2[j]; }
  #pragma unroll
  for (int j = 0; j < 16; ++j) m = fmaxf(m, v[j]);
  #pragma unroll
  for (int off = 32; off > 0; off >>= 1) m = fmaxf(m, __shfl_xor(m, off));
  __shared__ float redm[4], redsum[4];
  if (lane == 0) redm[wave] = m;
  __syncthreads();
  m = fmaxf(fmaxf(redm[0], redm[1]), fmaxf(redm[2], redm[3]));
  float sum = 0.f;
  #pragma unroll
  for (int j = 0; j < 16; ++j) { v[j] = __expf(v[j] - m); sum += v[j]; }
  #pragma unroll
  for (int off = 32; off > 0; off >>= 1) sum += __shfl_xor(sum, off);
  if (lane == 0) redsum[wave] = sum;
  __syncthreads();
  sum = redsum[0] + redsum[1] + redsum[2] + redsum[3];
  const float r = 1.f / sum;
  bf16x8 oa, ob;
  #pragma unroll
  for (int j = 0; j < 8; ++j) { oa[j] = (bf16)(v[j] * r); ob[j] = (bf16)(v[8 + j] * r); }
  ((bf16x8*)p)[tid] = oa;
  ((bf16x8*)p)[256 + tid] = ob;
}

// ---------------- MFMA GEMM: C[M][N] = A[M][K] @ Bt[N][K]^T (+ epilogue) ----
// EPI: 0 = +bias then *scale on cols<CCH, bf16 out (QKV proj)
//      1 = plain bf16 out (scores / PV)
//      2 = +bias +residual, f32 out (out-proj)
template <int BMt, int BNt, int EPI>
__global__ __launch_bounds__(256) void gemm_bt(
    const bf16* __restrict__ A, int lda, size_t sA,
    const bf16* __restrict__ Bt, int ldb, size_t sB,
    void* __restrict__ C, int ldc, size_t sC,
    const float* __restrict__ bias, const float* __restrict__ resid,
    int M, int N, int K, float scale) {
  constexpr int BK = 64;
  __shared__ bf16 Al[BMt * BK];
  __shared__ bf16 Bl[BNt * BK];
  A += (size_t)blockIdx.y * sA;
  Bt += (size_t)blockIdx.y * sB;
  const int tid = threadIdx.x;
  const int lane = tid & 63;
  const int wave = tid >> 6;
  const int fr = lane & 15;
  const int fq = lane >> 4;
  const int nbn = N / BNt;
  const int bm = blockIdx.x / nbn, bn = blockIdx.x % nbn;
  const int wr = wave >> 1, wc = wave & 1;
  constexpr int MF = BMt / 32;
  constexpr int NF = BNt / 32;
  constexpr int AIT = (BMt * BK) / (8 * 256);
  constexpr int BIT = (BNt * BK) / (8 * 256);

  f32x4 acc[MF][NF];
  #pragma unroll
  for (int m2 = 0; m2 < MF; ++m2)
    #pragma unroll
    for (int n2 = 0; n2 < NF; ++n2)
      acc[m2][n2] = f32x4{0.f, 0.f, 0.f, 0.f};

  for (int kt = 0; kt < K; kt += BK) {
    #pragma unroll
    for (int i = 0; i < AIT; ++i) {
      const int c = i * 256 + wave * 64 + lane;
      const int r = c >> 3, col = c & 7;
      gload_lds16(A + (size_t)(bm * BMt + r) * lda + kt + col * 8,
                  Al + (size_t)(i * 256 + wave * 64) * 8);
    }
    #pragma unroll
    for (int i = 0; i < BIT; ++i) {
      const int c = i * 256 + wave * 64 + lane;
      const int r = c >> 3, col = c & 7;
      gload_lds16(Bt + (size_t)(bn * BNt + r) * ldb + kt + col * 8,
                  Bl + (size_t)(i * 256 + wave * 64) * 8);
    }
    __syncthreads();
    #pragma unroll
    for (int kk = 0; kk < BK; kk += 32) {
      bf16x8 af[MF], bfg[NF];
      #pragma unroll
      for (int m2 = 0; m2 < MF; ++m2)
        af[m2] = *reinterpret_cast<const bf16x8*>(
            &Al[(size_t)(wr * (BMt / 2) + m2 * 16 + fr) * BK + kk + fq * 8]);
      #pragma unroll
      for (int n2 = 0; n2 < NF; ++n2)
        bfg[n2] = *reinterpret_cast<const bf16x8*>(
            &Bl[(size_t)(wc * (BNt / 2) + n2 * 16 + fr) * BK + kk + fq * 8]);
      #pragma unroll
      for (int m2 = 0; m2 < MF; ++m2)
        #pragma unroll
        for (int n2 = 0; n2 < NF; ++n2)
          acc[m2][n2] = __builtin_amdgcn_mfma_f32_16x16x32_bf16(
              af[m2], bfg[n2], acc[m2][n2], 0, 0, 0);
    }
    __syncthreads();
  }

  char* Cb = (char*)C + (size_t)blockIdx.y * sC * ((EPI == 2) ? 4 : 2);
  #pragma unroll
  for (int m2 = 0; m2 < MF; ++m2) {
    #pragma unroll
    for (int n2 = 0; n2 < NF; ++n2) {
      #pragma unroll
      for (int j = 0; j < 4; ++j) {
        const int row = bm * BMt + wr * (BMt / 2) + m2 * 16 + fq * 4 + j;
        const int col = bn * BNt + wc * (BNt / 2) + n2 * 16 + fr;
        const float val = acc[m2][n2][j];
        const size_t idx = (size_t)row * ldc + col;
        if constexpr (EPI == 0) {
          float vv = val + bias[col];
          if (col < CCH) vv *= scale;
          ((bf16*)Cb)[idx] = (bf16)vv;
        } else if constexpr (EPI == 1) {
          ((bf16*)Cb)[idx] = (bf16)val;
        } else {
          ((float*)Cb)[idx] = val + bias[col] + resid[idx];
        }
      }
    }
  }
}

// ---------------------------------------------------------------------------
extern "C" void kernel_launch(void* const* d_in, const int* in_sizes, int n_in,
                              void* d_out, int out_size, void* d_ws, size_t ws_size,
                              hipStream_t stream) {
  const float* x   = (const float*)d_in[0];
  const float* gsc = (const float*)d_in[1];
  const float* gbi = (const float*)d_in[2];
  const float* wq  = (const float*)d_in[3];
  const float* bq  = (const float*)d_in[4];
  const float* wk  = (const float*)d_in[5];
  const float* bk  = (const float*)d_in[6];
  const float* wv  = (const float*)d_in[7];
  const float* bv  = (const float*)d_in[8];
  const float* wo  = (const float*)d_in[9];
  const float* bo  = (const float*)d_in[10];
  float* out = (float*)d_out;
  char* ws = (char*)d_ws;

  const float sscale = 0.044194173824159216f;  // 1/sqrt(512)
  const bool batched = ws_size >= 203496448ULL;

  if (batched) {
    // S_all[134.2M] | qkv[50.3M] | vt[16.8M] | wT[2.1M] | bcat | stats | partials
    bf16*  S_all = (bf16*)(ws + 0);
    bf16*  hf    = (bf16*)(ws + 0);             // alias: dead before S written
    bf16*  qkv   = (bf16*)(ws + 134217728);
    bf16*  o     = (bf16*)(ws + 134217728);     // alias: qkv dead before PV
    bf16*  vt    = (bf16*)(ws + 184549376);
    bf16*  wT    = (bf16*)(ws + 201326592);
    float* bcat  = (float*)(ws + 203423744);
    float* stats = (float*)(ws + 203429888);
    float* parts = (float*)(ws + 203430912);

    gn_partial<<<dim3(64, NB), 256, 0, stream>>>((const float4*)x, parts);
    gn_reduce<<<1, 128, 0, stream>>>(parts, stats);
    gn_apply<<<8192, 256, 0, stream>>>((const float4*)x, stats, gsc, gbi, hf);
    wcast_t<<<dim3(64, 4), 256, 0, stream>>>(wq, wk, wv, wo, bq, bk, bv, wT, bcat);

    // fused QKV: [16384,512] @ [1536,512]^T -> [16384,1536] (q scaled)
    gemm_bt<128, 128, 0><<<dim3(1536, 1), 256, 0, stream>>>(
        hf, 512, 0, wT, 512, 0, qkv, 1536, 0, bcat, nullptr, 16384, 1536, 512, sscale);
    vtrans<<<dim3(512, NB), 256, 0, stream>>>(qkv, vt);
    // scores (bf16): per batch q @ k^T
    gemm_bt<128, 128, 1><<<dim3(1024, NB), 256, 0, stream>>>(
        qkv, 1536, (size_t)NTOK * 1536, qkv + 512, 1536, (size_t)NTOK * 1536,
        S_all, NTOK, (size_t)NTOK * NTOK, nullptr, nullptr, NTOK, NTOK, CCH, 0.f);
    softmax_rows_bf16<<<dim3(NTOK, NB), 256, 0, stream>>>(S_all);
    // o = P @ V
    gemm_bt<128, 64, 1><<<dim3(256, NB), 256, 0, stream>>>(
        S_all, NTOK, (size_t)NTOK * NTOK, vt, NTOK, (size_t)CCH * NTOK,
        o, CCH, (size_t)NTOK * CCH, nullptr, nullptr, NTOK, CCH, NTOK, 0.f);
    // out = x + o @ wo^T + bo
    gemm_bt<128, 128, 2><<<dim3(512, 1), 256, 0, stream>>>(
        o, 512, 0, wT + 786432, 512, 0, out, 512, 0, bo, x, 16384, 512, 512, 0.f);
  } else {
    // fallback (per-batch S): S1[33.6M] | qkv[50.3M] | vt[16.8M] | o[16.8M] | wT...
    bf16*  S1    = (bf16*)(ws + 0);
    bf16*  hf    = (bf16*)(ws + 0);
    bf16*  qkv   = (bf16*)(ws + 33554432);
    bf16*  vt    = (bf16*)(ws + 83886080);
    bf16*  o     = (bf16*)(ws + 100663296);
    bf16*  wT    = (bf16*)(ws + 117440512);
    float* bcat  = (float*)(ws + 119537664);
    float* stats = (float*)(ws + 119543808);
    float* parts = (float*)(ws + 119544832);

    gn_partial<<<dim3(64, NB), 256, 0, stream>>>((const float4*)x, parts);
    gn_reduce<<<1, 128, 0, stream>>>(parts, stats);
    gn_apply<<<8192, 256, 0, stream>>>((const float4*)x, stats, gsc, gbi, hf);
    wcast_t<<<dim3(64, 4), 256, 0, stream>>>(wq, wk, wv, wo, bq, bk, bv, wT, bcat);
    gemm_bt<128, 128, 0><<<dim3(1536, 1), 256, 0, stream>>>(
        hf, 512, 0, wT, 512, 0, qkv, 1536, 0, bcat, nullptr, 16384, 1536, 512, sscale);
    vtrans<<<dim3(512, NB), 256, 0, stream>>>(qkv, vt);
    for (int b = 0; b < NB; ++b) {
      const bf16* qb = qkv + (size_t)b * NTOK * 1536;
      gemm_bt<128, 128, 1><<<dim3(1024, 1), 256, 0, stream>>>(
          qb, 1536, 0, qb + 512, 1536, 0, S1, NTOK, 0, nullptr, nullptr,
          NTOK, NTOK, CCH, 0.f);
      softmax_rows_bf16<<<dim3(NTOK, 1), 256, 0, stream>>>(S1);
      gemm_bt<128, 64, 1><<<dim3(256, 1), 256, 0, stream>>>(
          S1, NTOK, 0, vt + (size_t)b * CCH * NTOK, NTOK, 0,
          o + (size_t)b * NTOK * CCH, CCH, 0, nullptr, nullptr, NTOK, CCH, NTOK, 0.f);
    }
    gemm_bt<128, 128, 2><<<dim3(512, 1), 256, 0, stream>>>(
        o, 512, 0, wT + 786432, 512, 0, out, 512, 0, bo, x, 16384, 512, 512, 0.f);
  }
}

// Round 3
// 398.000 us; speedup vs baseline: 1.7309x; 1.0454x over previous
//
#include <hip/hip_runtime.h>
#include <hip/hip_bf16.h>
#include <math.h>

// ---------------------------------------------------------------------------
// FlaxLTX2AudioAttnBlock: GN -> QKV proj -> softmax(QK^T/sqrt(C)) V -> proj -> +x
// B=4, N=4096 tokens/batch, C=512, G=32 groups.
// R3: fold wo into wv (W' = wv@wo, bias bpv = bv@wo+bo) -> out-proj GEMM gone,
//     PV writes final f32 output (+bias +residual). PV BN 64->128 (halve P
//     over-fetch). XCD-aware block swizzle on all GEMMs.
// ---------------------------------------------------------------------------

typedef __bf16 bf16;
typedef float f32x4 __attribute__((ext_vector_type(4)));
typedef __bf16 bf16x8 __attribute__((ext_vector_type(8)));
typedef __bf16 bf16x4 __attribute__((ext_vector_type(4)));

#define AS1 __attribute__((address_space(1)))
#define AS3 __attribute__((address_space(3)))

#define NB   4
#define NTOK 4096
#define CCH  512
#define NGRP 32

__device__ __forceinline__ void gload_lds16(const void* g, void* l) {
  __builtin_amdgcn_global_load_lds((AS1 void*)(g), (AS3 void*)(l), 16, 0, 0);
}

// ---------------- GroupNorm stage 1: partial sums ---------------------------
__global__ __launch_bounds__(256) void gn_partial(const float4* __restrict__ x4,
                                                  float* __restrict__ partials) {
  const int chunk = blockIdx.x, b = blockIdx.y;
  const int tid = threadIdx.x;
  const size_t base = ((size_t)b * NTOK + (size_t)chunk * 64) * 128;  // float4s
  float s = 0.f, ss = 0.f;
  #pragma unroll 4
  for (int it = 0; it < 32; ++it) {
    const float4 v = x4[base + it * 256 + tid];
    s  += v.x + v.y + v.z + v.w;
    ss += v.x * v.x + v.y * v.y + v.z * v.z + v.w * v.w;
  }
  __shared__ float ls[256], lss[256];
  ls[tid] = s; lss[tid] = ss;
  __syncthreads();
  if (tid < 32) {
    float ps = 0.f, pss = 0.f;
    #pragma unroll
    for (int j = 0; j < 4; ++j) {
      ps  += ls[tid * 4 + j] + ls[128 + tid * 4 + j];
      pss += lss[tid * 4 + j] + lss[128 + tid * 4 + j];
    }
    const size_t o = (((size_t)b * 64 + chunk) * 32 + tid) * 2;
    partials[o] = ps; partials[o + 1] = pss;
  }
}

// ---------------- GroupNorm stage 2: reduce 64 chunks -> stats --------------
__global__ __launch_bounds__(128) void gn_reduce(const float* __restrict__ partials,
                                                 float* __restrict__ stats) {
  const int tid = threadIdx.x;          // tid = b*32 + g
  const int b = tid >> 5, g = tid & 31;
  float s = 0.f, ss = 0.f;
  for (int c = 0; c < 64; ++c) {
    const size_t o = (((size_t)b * 64 + c) * 32 + g) * 2;
    s += partials[o]; ss += partials[o + 1];
  }
  const float inv = 1.f / (NTOK * 16.f);
  const float mean = s * inv;
  const float var = ss * inv - mean * mean;
  stats[tid * 2] = mean;
  stats[tid * 2 + 1] = rsqrtf(var + 1e-6f);
}

// ---------------- normalize + affine + cast to bf16 -------------------------
__global__ __launch_bounds__(256) void gn_apply(const float4* __restrict__ x4,
                                                const float* __restrict__ stats,
                                                const float* __restrict__ gsc,
                                                const float* __restrict__ gbi,
                                                bf16* __restrict__ hf) {
  const int i = blockIdx.x * 256 + threadIdx.x;   // over 2,097,152 float4s
  const float4 v = x4[i];
  const size_t e = (size_t)i * 4;
  const int c = (int)(e & (CCH - 1));
  const int b = (int)(e >> 21);
  const int g = c >> 4;
  const float mean = stats[(b * NGRP + g) * 2];
  const float rstd = stats[(b * NGRP + g) * 2 + 1];
  bf16x4 o;
  o[0] = (bf16)((v.x - mean) * rstd * gsc[c + 0] + gbi[c + 0]);
  o[1] = (bf16)((v.y - mean) * rstd * gsc[c + 1] + gbi[c + 1]);
  o[2] = (bf16)((v.z - mean) * rstd * gsc[c + 2] + gbi[c + 2]);
  o[3] = (bf16)((v.w - mean) * rstd * gsc[c + 3] + gbi[c + 3]);
  *reinterpret_cast<bf16x4*>(&hf[e]) = o;
}

// ---------------- weight transpose+cast (wq, wk) + bias concat --------------
__global__ __launch_bounds__(256) void wcast_t(const float* __restrict__ wq,
                                               const float* __restrict__ wk,
                                               const float* __restrict__ bq,
                                               const float* __restrict__ bk,
                                               bf16* __restrict__ dst,
                                               float* __restrict__ bcat) {
  const int w = blockIdx.y;                // 0 = wq, 1 = wk
  const float* src = (w == 0) ? wq : wk;
  bf16* out = dst + (size_t)w * CCH * CCH;
  const int t = blockIdx.x;                // 8x8 tiles of 64x64
  const int tr = t >> 3, tc = t & 7;
  if (t == 0) {
    const float* bsrc = (w == 0) ? bq : bk;
    for (int i = threadIdx.x; i < CCH; i += 256) {
      bcat[w * CCH + i] = bsrc[i];
      if (w == 0) bcat[2 * CCH + i] = 0.f;   // v' bias folded into bpv
    }
  }
  __shared__ float tile[64][65];
  for (int i = threadIdx.x; i < 4096; i += 256) {
    const int r = i >> 6, c = i & 63;
    tile[r][c] = src[(size_t)(tr * 64 + r) * CCH + tc * 64 + c];
  }
  __syncthreads();
  for (int i = threadIdx.x; i < 4096; i += 256) {
    const int r = i >> 6, c = i & 63;
    out[(size_t)(tc * 64 + r) * CCH + tr * 64 + c] = (bf16)tile[c][r];
  }
}

// ---------------- prep: W'^T = (wv@wo)^T in bf16 ----------------------------
// wpT[a][b] = W'[b][a] = sum_k wv[b][k] * wo[k][a]
__global__ __launch_bounds__(256) void prep_w(const float* __restrict__ wv,
                                              const float* __restrict__ wo,
                                              bf16* __restrict__ wpT) {
  const int ta = blockIdx.x >> 3, tb = blockIdx.x & 7;   // 8x8 blocks of 64x64
  __shared__ float woS[64][65];   // [kk][aa]
  __shared__ float wvS[64][65];   // [bb][kk]
  const int t = threadIdx.x;
  const int aa0 = (t & 15) * 4, bb0 = (t >> 4) * 4;
  float acc[4][4] = {};
  for (int kt = 0; kt < CCH; kt += 64) {
    for (int i = t; i < 4096; i += 256) {
      const int r = i >> 6, c = i & 63;
      woS[r][c] = wo[(size_t)(kt + r) * CCH + ta * 64 + c];
      wvS[r][c] = wv[(size_t)(tb * 64 + r) * CCH + kt + c];
    }
    __syncthreads();
    #pragma unroll 8
    for (int kk = 0; kk < 64; ++kk) {
      float wo4[4], wv4[4];
      #pragma unroll
      for (int i2 = 0; i2 < 4; ++i2) { wo4[i2] = woS[kk][aa0 + i2]; wv4[i2] = wvS[bb0 + i2][kk]; }
      #pragma unroll
      for (int a2 = 0; a2 < 4; ++a2)
        #pragma unroll
        for (int b2 = 0; b2 < 4; ++b2)
          acc[a2][b2] += wo4[a2] * wv4[b2];
    }
    __syncthreads();
  }
  #pragma unroll
  for (int a2 = 0; a2 < 4; ++a2)
    #pragma unroll
    for (int b2 = 0; b2 < 4; ++b2)
      wpT[(size_t)(ta * 64 + aa0 + a2) * CCH + tb * 64 + bb0 + b2] = (bf16)acc[a2][b2];
}

// ---------------- prep: bpv = bv @ wo + bo ----------------------------------
__global__ __launch_bounds__(512) void prep_b(const float* __restrict__ bv,
                                              const float* __restrict__ wo,
                                              const float* __restrict__ bo,
                                              float* __restrict__ bpv) {
  const int j = threadIdx.x;
  float acc = bo[j];
  for (int k2 = 0; k2 < CCH; ++k2) acc += bv[k2] * wo[(size_t)k2 * CCH + j];
  bpv[j] = acc;
}

// ---------------- bf16 transpose: qkv v'-cols [tok][1536] -> vt[d][tok] -----
__global__ __launch_bounds__(256) void vtrans(const bf16* __restrict__ qkv,
                                              bf16* __restrict__ vt) {
  const int b = blockIdx.y;
  const bf16* src = qkv + (size_t)b * NTOK * 1536 + 1024;   // v' columns
  bf16* out = vt + (size_t)b * CCH * NTOK;
  const int t = blockIdx.x;                // 64x8 tiles of 64x64
  const int tr = t >> 3, tc = t & 7;
  __shared__ bf16 tile[64][65];
  for (int i = threadIdx.x; i < 4096; i += 256) {
    const int r = i >> 6, c = i & 63;
    tile[r][c] = src[(size_t)(tr * 64 + r) * 1536 + tc * 64 + c];
  }
  __syncthreads();
  for (int i = threadIdx.x; i < 4096; i += 256) {
    const int r = i >> 6, c = i & 63;
    out[(size_t)(tc * 64 + r) * NTOK + tr * 64 + c] = tile[c][r];
  }
}

// ---------------- row softmax, bf16 in-place --------------------------------
__global__ __launch_bounds__(256) void softmax_rows_bf16(bf16* __restrict__ Sall) {
  const size_t row = (size_t)blockIdx.y * NTOK + blockIdx.x;
  bf16* p = Sall + row * NTOK;
  const int tid = threadIdx.x, lane = tid & 63, wave = tid >> 6;
  const bf16x8 a = ((const bf16x8*)p)[tid];
  const bf16x8 b2 = ((const bf16x8*)p)[256 + tid];
  float v[16];
  float m = -1e30f;
  #pragma unroll
  for (int j = 0; j < 8; ++j) { v[j] = (float)a[j]; v[8 + j] = (float)b2[j]; }
  #pragma unroll
  for (int j = 0; j < 16; ++j) m = fmaxf(m, v[j]);
  #pragma unroll
  for (int off = 32; off > 0; off >>= 1) m = fmaxf(m, __shfl_xor(m, off));
  __shared__ float redm[4], redsum[4];
  if (lane == 0) redm[wave] = m;
  __syncthreads();
  m = fmaxf(fmaxf(redm[0], redm[1]), fmaxf(redm[2], redm[3]));
  float sum = 0.f;
  #pragma unroll
  for (int j = 0; j < 16; ++j) { v[j] = __expf(v[j] - m); sum += v[j]; }
  #pragma unroll
  for (int off = 32; off > 0; off >>= 1) sum += __shfl_xor(sum, off);
  if (lane == 0) redsum[wave] = sum;
  __syncthreads();
  sum = redsum[0] + redsum[1] + redsum[2] + redsum[3];
  const float r = 1.f / sum;
  bf16x8 oa, ob;
  #pragma unroll
  for (int j = 0; j < 8; ++j) { oa[j] = (bf16)(v[j] * r); ob[j] = (bf16)(v[8 + j] * r); }
  ((bf16x8*)p)[tid] = oa;
  ((bf16x8*)p)[256 + tid] = ob;
}

// ---------------- MFMA GEMM: C[M][N] = A[M][K] @ Bt[N][K]^T (+ epilogue) ----
// EPI: 0 = +bias then *scale on cols<CCH, bf16 out (QKV proj)
//      1 = plain bf16 out (scores)
//      2 = +bias +residual, f32 out (PV -> final output)
template <int BMt, int BNt, int EPI>
__global__ __launch_bounds__(256) void gemm_bt(
    const bf16* __restrict__ A, int lda, size_t sA,
    const bf16* __restrict__ Bt, int ldb, size_t sB,
    void* __restrict__ C, int ldc, size_t sC,
    const float* __restrict__ bias, const float* __restrict__ resid,
    int M, int N, int K, float scale) {
  constexpr int BK = 64;
  __shared__ bf16 Al[BMt * BK];
  __shared__ bf16 Bl[BNt * BK];
  A += (size_t)blockIdx.y * sA;
  Bt += (size_t)blockIdx.y * sB;
  const int tid = threadIdx.x;
  const int lane = tid & 63;
  const int wave = tid >> 6;
  const int fr = lane & 15;
  const int fq = lane >> 4;
  const int nbn = N / BNt;
  // XCD-aware bijective swizzle (grid.x % 8 == 0 for all our launches)
  int bx = blockIdx.x;
  const int nwg = gridDim.x;
  if ((nwg & 7) == 0) bx = (bx & 7) * (nwg >> 3) + (bx >> 3);
  const int bm = bx / nbn, bn = bx % nbn;
  const int wr = wave >> 1, wc = wave & 1;
  constexpr int MF = BMt / 32;
  constexpr int NF = BNt / 32;
  constexpr int AIT = (BMt * BK) / (8 * 256);
  constexpr int BIT = (BNt * BK) / (8 * 256);

  f32x4 acc[MF][NF];
  #pragma unroll
  for (int m2 = 0; m2 < MF; ++m2)
    #pragma unroll
    for (int n2 = 0; n2 < NF; ++n2)
      acc[m2][n2] = f32x4{0.f, 0.f, 0.f, 0.f};

  for (int kt = 0; kt < K; kt += BK) {
    #pragma unroll
    for (int i = 0; i < AIT; ++i) {
      const int c = i * 256 + wave * 64 + lane;
      const int r = c >> 3, col = c & 7;
      gload_lds16(A + (size_t)(bm * BMt + r) * lda + kt + col * 8,
                  Al + (size_t)(i * 256 + wave * 64) * 8);
    }
    #pragma unroll
    for (int i = 0; i < BIT; ++i) {
      const int c = i * 256 + wave * 64 + lane;
      const int r = c >> 3, col = c & 7;
      gload_lds16(Bt + (size_t)(bn * BNt + r) * ldb + kt + col * 8,
                  Bl + (size_t)(i * 256 + wave * 64) * 8);
    }
    __syncthreads();
    #pragma unroll
    for (int kk = 0; kk < BK; kk += 32) {
      bf16x8 af[MF], bfg[NF];
      #pragma unroll
      for (int m2 = 0; m2 < MF; ++m2)
        af[m2] = *reinterpret_cast<const bf16x8*>(
            &Al[(size_t)(wr * (BMt / 2) + m2 * 16 + fr) * BK + kk + fq * 8]);
      #pragma unroll
      for (int n2 = 0; n2 < NF; ++n2)
        bfg[n2] = *reinterpret_cast<const bf16x8*>(
            &Bl[(size_t)(wc * (BNt / 2) + n2 * 16 + fr) * BK + kk + fq * 8]);
      #pragma unroll
      for (int m2 = 0; m2 < MF; ++m2)
        #pragma unroll
        for (int n2 = 0; n2 < NF; ++n2)
          acc[m2][n2] = __builtin_amdgcn_mfma_f32_16x16x32_bf16(
              af[m2], bfg[n2], acc[m2][n2], 0, 0, 0);
    }
    __syncthreads();
  }

  #pragma unroll
  for (int m2 = 0; m2 < MF; ++m2) {
    #pragma unroll
    for (int n2 = 0; n2 < NF; ++n2) {
      #pragma unroll
      for (int j = 0; j < 4; ++j) {
        const int row = bm * BMt + wr * (BMt / 2) + m2 * 16 + fq * 4 + j;
        const int col = bn * BNt + wc * (BNt / 2) + n2 * 16 + fr;
        const float val = acc[m2][n2][j];
        const size_t idx = (size_t)row * ldc + col;
        if constexpr (EPI == 0) {
          float vv = val + bias[col];
          if (col < CCH) vv *= scale;
          ((bf16*)C)[(size_t)blockIdx.y * sC + idx] = (bf16)vv;
        } else if constexpr (EPI == 1) {
          ((bf16*)C)[(size_t)blockIdx.y * sC + idx] = (bf16)val;
        } else {
          float* Cf = (float*)C + (size_t)blockIdx.y * sC;
          const float* rz = resid + (size_t)blockIdx.y * sC;
          Cf[idx] = val + bias[col] + rz[idx];
        }
      }
    }
  }
}

// ---------------------------------------------------------------------------
extern "C" void kernel_launch(void* const* d_in, const int* in_sizes, int n_in,
                              void* d_out, int out_size, void* d_ws, size_t ws_size,
                              hipStream_t stream) {
  const float* x   = (const float*)d_in[0];
  const float* gsc = (const float*)d_in[1];
  const float* gbi = (const float*)d_in[2];
  const float* wq  = (const float*)d_in[3];
  const float* bq  = (const float*)d_in[4];
  const float* wk  = (const float*)d_in[5];
  const float* bk  = (const float*)d_in[6];
  const float* wv  = (const float*)d_in[7];
  const float* bv  = (const float*)d_in[8];
  const float* wo  = (const float*)d_in[9];
  const float* bo  = (const float*)d_in[10];
  float* out = (float*)d_out;
  char* ws = (char*)d_ws;

  const float sscale = 0.044194173824159216f;  // 1/sqrt(512)
  const bool batched = ws_size >= 203496448ULL;

  if (batched) {
    // S_all[134.2M] | qkv[50.3M] | vt[16.8M] | wT[2.1M incl W'T + bpv] | extras
    bf16*  S_all = (bf16*)(ws + 0);
    bf16*  hf    = (bf16*)(ws + 0);             // alias: dead before S written
    bf16*  qkv   = (bf16*)(ws + 134217728);
    bf16*  vt    = (bf16*)(ws + 184549376);
    bf16*  wT    = (bf16*)(ws + 201326592);     // slots: wqT | wkT | W'T | free
    float* bpv   = (float*)(ws + 202899456);    // in unused slot 3
    float* bcat  = (float*)(ws + 203423744);
    float* stats = (float*)(ws + 203429888);
    float* parts = (float*)(ws + 203430912);

    gn_partial<<<dim3(64, NB), 256, 0, stream>>>((const float4*)x, parts);
    gn_reduce<<<1, 128, 0, stream>>>(parts, stats);
    gn_apply<<<8192, 256, 0, stream>>>((const float4*)x, stats, gsc, gbi, hf);
    wcast_t<<<dim3(64, 2), 256, 0, stream>>>(wq, wk, bq, bk, wT, bcat);
    prep_w<<<64, 256, 0, stream>>>(wv, wo, wT + 2 * CCH * CCH);
    prep_b<<<1, 512, 0, stream>>>(bv, wo, bo, bpv);

    // fused QKV': [16384,512] @ [1536,512]^T -> [16384,1536] (q scaled)
    gemm_bt<128, 128, 0><<<dim3(1536, 1), 256, 0, stream>>>(
        hf, 512, 0, wT, 512, 0, qkv, 1536, 0, bcat, nullptr, 16384, 1536, 512, sscale);
    vtrans<<<dim3(512, NB), 256, 0, stream>>>(qkv, vt);
    // scores (bf16): per batch q @ k^T
    gemm_bt<128, 128, 1><<<dim3(1024, NB), 256, 0, stream>>>(
        qkv, 1536, (size_t)NTOK * 1536, qkv + 512, 1536, (size_t)NTOK * 1536,
        S_all, NTOK, (size_t)NTOK * NTOK, nullptr, nullptr, NTOK, NTOK, CCH, 0.f);
    softmax_rows_bf16<<<dim3(NTOK, NB), 256, 0, stream>>>(S_all);
    // out = x + P @ V' + bpv   (final, f32)
    gemm_bt<128, 128, 2><<<dim3(128, NB), 256, 0, stream>>>(
        S_all, NTOK, (size_t)NTOK * NTOK, vt, NTOK, (size_t)CCH * NTOK,
        out, CCH, (size_t)NTOK * CCH, bpv, x, NTOK, CCH, NTOK, 0.f);
  } else {
    // fallback (per-batch S): S1[33.6M] | qkv[50.3M] | vt[16.8M] | wT | extras
    bf16*  S1    = (bf16*)(ws + 0);
    bf16*  hf    = (bf16*)(ws + 0);
    bf16*  qkv   = (bf16*)(ws + 33554432);
    bf16*  vt    = (bf16*)(ws + 83886080);
    bf16*  wT    = (bf16*)(ws + 100663296);
    float* bpv   = (float*)(ws + 102236160);    // unused slot 3
    float* bcat  = (float*)(ws + 102760448);
    float* stats = (float*)(ws + 102766592);
    float* parts = (float*)(ws + 102767616);

    gn_partial<<<dim3(64, NB), 256, 0, stream>>>((const float4*)x, parts);
    gn_reduce<<<1, 128, 0, stream>>>(parts, stats);
    gn_apply<<<8192, 256, 0, stream>>>((const float4*)x, stats, gsc, gbi, hf);
    wcast_t<<<dim3(64, 2), 256, 0, stream>>>(wq, wk, bq, bk, wT, bcat);
    prep_w<<<64, 256, 0, stream>>>(wv, wo, wT + 2 * CCH * CCH);
    prep_b<<<1, 512, 0, stream>>>(bv, wo, bo, bpv);
    gemm_bt<128, 128, 0><<<dim3(1536, 1), 256, 0, stream>>>(
        hf, 512, 0, wT, 512, 0, qkv, 1536, 0, bcat, nullptr, 16384, 1536, 512, sscale);
    vtrans<<<dim3(512, NB), 256, 0, stream>>>(qkv, vt);
    for (int b = 0; b < NB; ++b) {
      const bf16* qb = qkv + (size_t)b * NTOK * 1536;
      gemm_bt<128, 128, 1><<<dim3(1024, 1), 256, 0, stream>>>(
          qb, 1536, 0, qb + 512, 1536, 0, S1, NTOK, 0, nullptr, nullptr,
          NTOK, NTOK, CCH, 0.f);
      softmax_rows_bf16<<<dim3(NTOK, 1), 256, 0, stream>>>(S1);
      gemm_bt<128, 128, 2><<<dim3(128, 1), 256, 0, stream>>>(
          S1, NTOK, 0, vt + (size_t)b * CCH * NTOK, NTOK, 0,
          out + (size_t)b * NTOK * CCH, CCH, 0, bpv, x + (size_t)b * NTOK * CCH,
          NTOK, CCH, NTOK, 0.f);
    }
  }
}

// Round 4
// 351.311 us; speedup vs baseline: 1.9609x; 1.1329x over previous
//
#include <hip/hip_runtime.h>
#include <hip/hip_bf16.h>
#include <math.h>

// ---------------------------------------------------------------------------
// FlaxLTX2AudioAttnBlock: GN -> QKV proj -> softmax(QK^T/sqrt(C)) V -> proj -> +x
// B=4, N=4096 tokens/batch, C=512, G=32 groups.
// R4: 8-phase 256xBN double-buffered MFMA GEMM (T2 chunk-XOR swizzle, T3/T4
//     counted vmcnt, T5 setprio). wo folded into wv (R3). bf16 scores.
// ---------------------------------------------------------------------------

typedef __bf16 bf16;
typedef float f32x4 __attribute__((ext_vector_type(4)));
typedef __bf16 bf16x8 __attribute__((ext_vector_type(8)));
typedef __bf16 bf16x4 __attribute__((ext_vector_type(4)));

#define AS1 __attribute__((address_space(1)))
#define AS3 __attribute__((address_space(3)))

#define NB   4
#define NTOK 4096
#define CCH  512
#define NGRP 32

__device__ __forceinline__ void gload_lds16(const void* g, void* l) {
  __builtin_amdgcn_global_load_lds((AS1 void*)(g), (AS3 void*)(l), 16, 0, 0);
}

// ---------------- GroupNorm stage 1: partial sums ---------------------------
__global__ __launch_bounds__(256) void gn_partial(const float4* __restrict__ x4,
                                                  float* __restrict__ partials) {
  const int chunk = blockIdx.x, b = blockIdx.y;
  const int tid = threadIdx.x;
  const size_t base = ((size_t)b * NTOK + (size_t)chunk * 64) * 128;  // float4s
  float s = 0.f, ss = 0.f;
  #pragma unroll 4
  for (int it = 0; it < 32; ++it) {
    const float4 v = x4[base + it * 256 + tid];
    s  += v.x + v.y + v.z + v.w;
    ss += v.x * v.x + v.y * v.y + v.z * v.z + v.w * v.w;
  }
  __shared__ float ls[256], lss[256];
  ls[tid] = s; lss[tid] = ss;
  __syncthreads();
  if (tid < 32) {
    float ps = 0.f, pss = 0.f;
    #pragma unroll
    for (int j = 0; j < 4; ++j) {
      ps  += ls[tid * 4 + j] + ls[128 + tid * 4 + j];
      pss += lss[tid * 4 + j] + lss[128 + tid * 4 + j];
    }
    const size_t o = (((size_t)b * 64 + chunk) * 32 + tid) * 2;
    partials[o] = ps; partials[o + 1] = pss;
  }
}

// ---------------- GroupNorm stage 2: reduce 64 chunks -> stats --------------
__global__ __launch_bounds__(128) void gn_reduce(const float* __restrict__ partials,
                                                 float* __restrict__ stats) {
  const int tid = threadIdx.x;          // tid = b*32 + g
  const int b = tid >> 5, g = tid & 31;
  float s = 0.f, ss = 0.f;
  for (int c = 0; c < 64; ++c) {
    const size_t o = (((size_t)b * 64 + c) * 32 + g) * 2;
    s += partials[o]; ss += partials[o + 1];
  }
  const float inv = 1.f / (NTOK * 16.f);
  const float mean = s * inv;
  const float var = ss * inv - mean * mean;
  stats[tid * 2] = mean;
  stats[tid * 2 + 1] = rsqrtf(var + 1e-6f);
}

// ---------------- normalize + affine + cast to bf16 -------------------------
__global__ __launch_bounds__(256) void gn_apply(const float4* __restrict__ x4,
                                                const float* __restrict__ stats,
                                                const float* __restrict__ gsc,
                                                const float* __restrict__ gbi,
                                                bf16* __restrict__ hf) {
  const int i = blockIdx.x * 256 + threadIdx.x;   // over 2,097,152 float4s
  const float4 v = x4[i];
  const size_t e = (size_t)i * 4;
  const int c = (int)(e & (CCH - 1));
  const int b = (int)(e >> 21);
  const int g = c >> 4;
  const float mean = stats[(b * NGRP + g) * 2];
  const float rstd = stats[(b * NGRP + g) * 2 + 1];
  bf16x4 o;
  o[0] = (bf16)((v.x - mean) * rstd * gsc[c + 0] + gbi[c + 0]);
  o[1] = (bf16)((v.y - mean) * rstd * gsc[c + 1] + gbi[c + 1]);
  o[2] = (bf16)((v.z - mean) * rstd * gsc[c + 2] + gbi[c + 2]);
  o[3] = (bf16)((v.w - mean) * rstd * gsc[c + 3] + gbi[c + 3]);
  *reinterpret_cast<bf16x4*>(&hf[e]) = o;
}

// ---------------- weight transpose+cast (wq, wk) + bias concat --------------
__global__ __launch_bounds__(256) void wcast_t(const float* __restrict__ wq,
                                               const float* __restrict__ wk,
                                               const float* __restrict__ bq,
                                               const float* __restrict__ bk,
                                               bf16* __restrict__ dst,
                                               float* __restrict__ bcat) {
  const int w = blockIdx.y;                // 0 = wq, 1 = wk
  const float* src = (w == 0) ? wq : wk;
  bf16* out = dst + (size_t)w * CCH * CCH;
  const int t = blockIdx.x;                // 8x8 tiles of 64x64
  const int tr = t >> 3, tc = t & 7;
  if (t == 0) {
    const float* bsrc = (w == 0) ? bq : bk;
    for (int i = threadIdx.x; i < CCH; i += 256) {
      bcat[w * CCH + i] = bsrc[i];
      if (w == 0) bcat[2 * CCH + i] = 0.f;   // v' bias folded into bpv
    }
  }
  __shared__ float tile[64][65];
  for (int i = threadIdx.x; i < 4096; i += 256) {
    const int r = i >> 6, c = i & 63;
    tile[r][c] = src[(size_t)(tr * 64 + r) * CCH + tc * 64 + c];
  }
  __syncthreads();
  for (int i = threadIdx.x; i < 4096; i += 256) {
    const int r = i >> 6, c = i & 63;
    out[(size_t)(tc * 64 + r) * CCH + tr * 64 + c] = (bf16)tile[c][r];
  }
}

// ---------------- prep: W'^T = (wv@wo)^T in bf16 ----------------------------
__global__ __launch_bounds__(256) void prep_w(const float* __restrict__ wv,
                                              const float* __restrict__ wo,
                                              bf16* __restrict__ wpT) {
  const int ta = blockIdx.x >> 3, tb = blockIdx.x & 7;   // 8x8 blocks of 64x64
  __shared__ float woS[64][65];   // [kk][aa]
  __shared__ float wvS[64][65];   // [bb][kk]
  const int t = threadIdx.x;
  const int aa0 = (t & 15) * 4, bb0 = (t >> 4) * 4;
  float acc[4][4] = {};
  for (int kt = 0; kt < CCH; kt += 64) {
    for (int i = t; i < 4096; i += 256) {
      const int r = i >> 6, c = i & 63;
      woS[r][c] = wo[(size_t)(kt + r) * CCH + ta * 64 + c];
      wvS[r][c] = wv[(size_t)(tb * 64 + r) * CCH + kt + c];
    }
    __syncthreads();
    #pragma unroll 8
    for (int kk = 0; kk < 64; ++kk) {
      float wo4[4], wv4[4];
      #pragma unroll
      for (int i2 = 0; i2 < 4; ++i2) { wo4[i2] = woS[kk][aa0 + i2]; wv4[i2] = wvS[bb0 + i2][kk]; }
      #pragma unroll
      for (int a2 = 0; a2 < 4; ++a2)
        #pragma unroll
        for (int b2 = 0; b2 < 4; ++b2)
          acc[a2][b2] += wo4[a2] * wv4[b2];
    }
    __syncthreads();
  }
  #pragma unroll
  for (int a2 = 0; a2 < 4; ++a2)
    #pragma unroll
    for (int b2 = 0; b2 < 4; ++b2)
      wpT[(size_t)(ta * 64 + aa0 + a2) * CCH + tb * 64 + bb0 + b2] = (bf16)acc[a2][b2];
}

// ---------------- prep: bpv = bv @ wo + bo ----------------------------------
__global__ __launch_bounds__(512) void prep_b(const float* __restrict__ bv,
                                              const float* __restrict__ wo,
                                              const float* __restrict__ bo,
                                              float* __restrict__ bpv) {
  const int j = threadIdx.x;
  float acc = bo[j];
  for (int k2 = 0; k2 < CCH; ++k2) acc += bv[k2] * wo[(size_t)k2 * CCH + j];
  bpv[j] = acc;
}

// ---------------- bf16 transpose: qkv v'-cols [tok][1536] -> vt[d][tok] -----
__global__ __launch_bounds__(256) void vtrans(const bf16* __restrict__ qkv,
                                              bf16* __restrict__ vt) {
  const int b = blockIdx.y;
  const bf16* src = qkv + (size_t)b * NTOK * 1536 + 1024;   // v' columns
  bf16* out = vt + (size_t)b * CCH * NTOK;
  const int t = blockIdx.x;                // 64x8 tiles of 64x64
  const int tr = t >> 3, tc = t & 7;
  __shared__ bf16 tile[64][65];
  for (int i = threadIdx.x; i < 4096; i += 256) {
    const int r = i >> 6, c = i & 63;
    tile[r][c] = src[(size_t)(tr * 64 + r) * 1536 + tc * 64 + c];
  }
  __syncthreads();
  for (int i = threadIdx.x; i < 4096; i += 256) {
    const int r = i >> 6, c = i & 63;
    out[(size_t)(tc * 64 + r) * NTOK + tr * 64 + c] = tile[c][r];
  }
}

// ---------------- row softmax, bf16 in-place --------------------------------
__global__ __launch_bounds__(256) void softmax_rows_bf16(bf16* __restrict__ Sall) {
  const size_t row = (size_t)blockIdx.y * NTOK + blockIdx.x;
  bf16* p = Sall + row * NTOK;
  const int tid = threadIdx.x, lane = tid & 63, wave = tid >> 6;
  const bf16x8 a = ((const bf16x8*)p)[tid];
  const bf16x8 b2 = ((const bf16x8*)p)[256 + tid];
  float v[16];
  float m = -1e30f;
  #pragma unroll
  for (int j = 0; j < 8; ++j) { v[j] = (float)a[j]; v[8 + j] = (float)b2[j]; }
  #pragma unroll
  for (int j = 0; j < 16; ++j) m = fmaxf(m, v[j]);
  #pragma unroll
  for (int off = 32; off > 0; off >>= 1) m = fmaxf(m, __shfl_xor(m, off));
  __shared__ float redm[4], redsum[4];
  if (lane == 0) redm[wave] = m;
  __syncthreads();
  m = fmaxf(fmaxf(redm[0], redm[1]), fmaxf(redm[2], redm[3]));
  float sum = 0.f;
  #pragma unroll
  for (int j = 0; j < 16; ++j) { v[j] = __expf(v[j] - m); sum += v[j]; }
  #pragma unroll
  for (int off = 32; off > 0; off >>= 1) sum += __shfl_xor(sum, off);
  if (lane == 0) redsum[wave] = sum;
  __syncthreads();
  sum = redsum[0] + redsum[1] + redsum[2] + redsum[3];
  const float r = 1.f / sum;
  bf16x8 oa, ob;
  #pragma unroll
  for (int j = 0; j < 8; ++j) { oa[j] = (bf16)(v[j] * r); ob[j] = (bf16)(v[8 + j] * r); }
  ((bf16x8*)p)[tid] = oa;
  ((bf16x8*)p)[256 + tid] = ob;
}

// ---------------- 8-phase 256xBN MFMA GEMM: C = A @ Bt^T (+ epilogue) -------
// 512 threads = 8 waves (2M x 4N). BM=256 fixed, BNt in {256,128}, BK=64.
// Double-buffered LDS; 2 K-tiles per iteration; counted vmcnt (T4); per-phase
// stage interleave (T3); setprio around MFMA (T5); chunk-XOR swizzle (T2,
// linear LDS dest + pre-swizzled global source + swizzled ds_read).
// Schedule invariants (verified by construction):
//  - stage into region R issues only after R's readers' phase-closing barrier
//  - vmcnt(VM) at ph4 leaves {ph3,ph4} stages in flight => all of tile t+1
//    landed before ph5/ph7/ph8 reads; vmcnt(VM) at ph8 leaves {ph7,ph8} =>
//    tile t+2 fully landed before next iteration's ph1-ph4 reads.
// EPI: 0 = +bias, *scale on cols<CCH, bf16 out (QKV) | 1 = plain bf16 out
//      (scores) | 2 = +bias +residual, f32 out (PV -> final output)
template <int BNt, int EPI>
__global__ __launch_bounds__(512, 2) void gemm256(
    const bf16* __restrict__ A, int lda, size_t sA,
    const bf16* __restrict__ Bt, int ldb, size_t sB,
    void* __restrict__ C, int ldc, size_t sC,
    const float* __restrict__ bias, const float* __restrict__ resid,
    int M, int N, int K, float scale) {
  constexpr int BK = 64;
  constexpr int WN = BNt / 4;        // per-wave N extent (64 or 32)
  constexpr int NREP = WN / 16;      // N fragments per wave (4 or 2)
  constexpr int QNF = NREP / 2;      // N frags per quadrant-phase (2 or 1)
  constexpr int BH = BNt / 2;        // B half-tile rows (128 or 64)
  constexpr int BISS = BNt / 128;    // gload issues per B half (2 or 1)

  __shared__ bf16 Al[2][256 * BK];
  __shared__ bf16 Bl[2][BNt * BK];

  A += (size_t)blockIdx.y * sA;
  Bt += (size_t)blockIdx.y * sB;

  const int tid = threadIdx.x;
  const int lane = tid & 63;
  const int wave = tid >> 6;
  const int wm = wave >> 2, wn = wave & 3;
  const int fr = lane & 15, fq = lane >> 4;
  const int nbn = N / BNt;
  int bx = blockIdx.x;
  const int nwg = gridDim.x;
  bx = (bx & 7) * (nwg >> 3) + (bx >> 3);    // XCD swizzle (all grids %8==0)
  const int bm = bx / nbn, bn = bx % nbn;

  // staging: thread covers 16B chunk; T2: global chunk = lds chunk ^ (row&7)
  const int srow = tid >> 3;                              // 0..63
  const int scol = (((tid & 7) ^ (srow & 7)) * 8);
  const bf16* Ab = A + (size_t)(bm * 256 + srow) * lda + scol;
  const bf16* Bb = Bt + (size_t)(bn * BNt + srow) * ldb + scol;

  // swizzled ds_read chunk offsets (elems): chunk (ks*4+fq) ^ (fr&7)
  const int xk = fr & 7;
  const int c0 = ((0 + fq) ^ xk) * 8;
  const int c1 = ((4 + fq) ^ xk) * 8;
  const int aroff = (wm * 128 + fr) * BK;
  const int broff = (wn * WN + fr) * BK;

  f32x4 acc[8][NREP];
  #pragma unroll
  for (int m2 = 0; m2 < 8; ++m2)
    #pragma unroll
    for (int n2 = 0; n2 < NREP; ++n2)
      acc[m2][n2] = f32x4{0.f, 0.f, 0.f, 0.f};
  bf16x8 af[4][2];
  bf16x8 bfr[QNF][2];

#define STAGE_A(buf, h, kt)                                                     \
  { gload_lds16(Ab + (size_t)((h) * 128) * lda + (kt),                          \
                &Al[buf][(h) * 8192 + wave * 512]);                             \
    gload_lds16(Ab + (size_t)((h) * 128 + 64) * lda + (kt),                     \
                &Al[buf][(h) * 8192 + 4096 + wave * 512]); }
#define STAGE_B(buf, h, kt)                                                     \
  { gload_lds16(Bb + (size_t)((h) * BH) * ldb + (kt),                           \
                &Bl[buf][(h) * BH * BK + wave * 512]);                          \
    if (BISS == 2)                                                              \
      gload_lds16(Bb + (size_t)((h) * BH + 64) * ldb + (kt),                    \
                  &Bl[buf][(h) * BH * BK + 4096 + wave * 512]); }
#define LOADA(buf, mh)                                                          \
  { _Pragma("unroll") for (int mi = 0; mi < 4; ++mi) {                          \
      af[mi][0] = *(const bf16x8*)&Al[buf][aroff + ((mh) * 64 + mi * 16) * BK + c0]; \
      af[mi][1] = *(const bf16x8*)&Al[buf][aroff + ((mh) * 64 + mi * 16) * BK + c1]; } }
#define LOADB(buf, nh)                                                          \
  { _Pragma("unroll") for (int ni = 0; ni < QNF; ++ni) {                        \
      bfr[ni][0] = *(const bf16x8*)&Bl[buf][broff + ((nh) * QNF * 16 + ni * 16) * BK + c0]; \
      bfr[ni][1] = *(const bf16x8*)&Bl[buf][broff + ((nh) * QNF * 16 + ni * 16) * BK + c1]; } }
#define MMA(mh, nh)                                                             \
  { __builtin_amdgcn_s_setprio(1);                                              \
    _Pragma("unroll") for (int mi = 0; mi < 4; ++mi)                            \
      _Pragma("unroll") for (int ni = 0; ni < QNF; ++ni) {                      \
        acc[(mh) * 4 + mi][(nh) * QNF + ni] = __builtin_amdgcn_mfma_f32_16x16x32_bf16( \
            af[mi][0], bfr[ni][0], acc[(mh) * 4 + mi][(nh) * QNF + ni], 0, 0, 0); \
        acc[(mh) * 4 + mi][(nh) * QNF + ni] = __builtin_amdgcn_mfma_f32_16x16x32_bf16( \
            af[mi][1], bfr[ni][1], acc[(mh) * 4 + mi][(nh) * QNF + ni], 0, 0, 0); } \
    __builtin_amdgcn_s_setprio(0); }
#define BARX() __builtin_amdgcn_s_barrier()
#define PIN() __builtin_amdgcn_sched_barrier(0)
#define LGKM0() { asm volatile("s_waitcnt lgkmcnt(0)" ::: "memory"); PIN(); }
#define VMW(n) asm volatile("s_waitcnt vmcnt(" #n ")" ::: "memory")
#define VMWSS() { if (BISS == 2) VMW(4); else VMW(3); }   // steady-state count

  // prologue: tile0 (4 halves) + A0,B0 of tile1 -> keep 2 halves in flight
  STAGE_A(0, 0, 0); STAGE_A(0, 1, 0);
  STAGE_B(0, 0, 0); STAGE_B(0, 1, 0);
  STAGE_A(1, 0, BK); STAGE_B(1, 0, BK);
  VMWSS();
  BARX();

  const int niter = K >> 7;      // 2 K-tiles (BK=64) per iteration
  for (int j = 0; j < niter; ++j) {
    const int kt1 = j * 128 + 64;
    const int kt2 = kt1 + 64, kt3 = kt1 + 128;
    const bool last = (j == niter - 1);
    // ph1: Q(0,0) of tile t (buf0); stage A1(t+1)->buf1
    LOADA(0, 0); LOADB(0, 0); STAGE_A(1, 1, kt1);
    PIN(); BARX(); LGKM0(); MMA(0, 0); BARX();
    // ph2: Q(0,1); stage B1(t+1)->buf1
    LOADB(0, 1); STAGE_B(1, 1, kt1);
    PIN(); BARX(); LGKM0(); MMA(0, 1); BARX();
    // ph3: Q(1,0); stage A0(t+2)->buf0.A0 (free after ph2)
    LOADA(0, 1); LOADB(0, 0); if (!last) STAGE_A(0, 0, kt2);
    PIN(); BARX(); LGKM0(); MMA(1, 0); BARX();
    // ph4: Q(1,1); stage B0(t+2)->buf0.B0 (free after ph3); counted vmcnt
    LOADB(0, 1); if (!last) STAGE_B(0, 0, kt2);
    PIN(); BARX(); LGKM0(); MMA(1, 1);
    if (last) { VMW(0); } else VMWSS();
    BARX();
    // ph5: Q(0,0) of tile t+1 (buf1); stage A1(t+2)->buf0.A1 (free after ph4)
    LOADA(1, 0); LOADB(1, 0); if (!last) STAGE_A(0, 1, kt2);
    PIN(); BARX(); LGKM0(); MMA(0, 0); BARX();
    // ph6: Q(0,1); stage B1(t+2)->buf0.B1 (free after ph4)
    LOADB(1, 1); if (!last) STAGE_B(0, 1, kt2);
    PIN(); BARX(); LGKM0(); MMA(0, 1); BARX();
    // ph7: Q(1,0); stage A0(t+3)->buf1.A0 (free after ph6)
    LOADA(1, 1); LOADB(1, 0); if (!last) STAGE_A(1, 0, kt3);
    PIN(); BARX(); LGKM0(); MMA(1, 0); BARX();
    // ph8: Q(1,1); stage B0(t+3)->buf1.B0 (free after ph7); counted vmcnt
    LOADB(1, 1); if (!last) STAGE_B(1, 0, kt3);
    PIN(); BARX(); LGKM0(); MMA(1, 1);
    if (!last) VMWSS();
    BARX();
  }

  // epilogue
  const int crow0 = bm * 256 + wm * 128 + fq * 4;
  const int ccol0 = bn * BNt + wn * WN + fr;
  #pragma unroll
  for (int mh = 0; mh < 2; ++mh)
    #pragma unroll
    for (int mi = 0; mi < 4; ++mi)
      #pragma unroll
      for (int nr = 0; nr < NREP; ++nr)
        #pragma unroll
        for (int jj = 0; jj < 4; ++jj) {
          const int row = crow0 + mh * 64 + mi * 16 + jj;
          const int col = ccol0 + nr * 16;
          const float val = acc[mh * 4 + mi][nr][jj];
          const size_t idx = (size_t)row * ldc + col;
          if constexpr (EPI == 0) {
            float vv = val + bias[col];
            if (col < CCH) vv *= scale;
            ((bf16*)C)[(size_t)blockIdx.y * sC + idx] = (bf16)vv;
          } else if constexpr (EPI == 1) {
            ((bf16*)C)[(size_t)blockIdx.y * sC + idx] = (bf16)val;
          } else {
            float* Cf = (float*)C + (size_t)blockIdx.y * sC;
            Cf[idx] = val + bias[col] + resid[(size_t)blockIdx.y * sC + idx];
          }
        }
#undef STAGE_A
#undef STAGE_B
#undef LOADA
#undef LOADB
#undef MMA
#undef BARX
#undef PIN
#undef LGKM0
#undef VMW
#undef VMWSS
}

// ---------------------------------------------------------------------------
extern "C" void kernel_launch(void* const* d_in, const int* in_sizes, int n_in,
                              void* d_out, int out_size, void* d_ws, size_t ws_size,
                              hipStream_t stream) {
  const float* x   = (const float*)d_in[0];
  const float* gsc = (const float*)d_in[1];
  const float* gbi = (const float*)d_in[2];
  const float* wq  = (const float*)d_in[3];
  const float* bq  = (const float*)d_in[4];
  const float* wk  = (const float*)d_in[5];
  const float* bk  = (const float*)d_in[6];
  const float* wv  = (const float*)d_in[7];
  const float* bv  = (const float*)d_in[8];
  const float* wo  = (const float*)d_in[9];
  const float* bo  = (const float*)d_in[10];
  float* out = (float*)d_out;
  char* ws = (char*)d_ws;

  const float sscale = 0.044194173824159216f;  // 1/sqrt(512)
  const bool batched = ws_size >= 203496448ULL;

  if (batched) {
    // S_all[134.2M] | qkv[50.3M] | vt[16.8M] | wT[2.1M incl W'T] | extras
    bf16*  S_all = (bf16*)(ws + 0);
    bf16*  hf    = (bf16*)(ws + 0);             // alias: dead before S written
    bf16*  qkv   = (bf16*)(ws + 134217728);
    bf16*  vt    = (bf16*)(ws + 184549376);
    bf16*  wT    = (bf16*)(ws + 201326592);     // slots: wqT | wkT | W'T | free
    float* bpv   = (float*)(ws + 202899456);    // in unused slot 3
    float* bcat  = (float*)(ws + 203423744);
    float* stats = (float*)(ws + 203429888);
    float* parts = (float*)(ws + 203430912);

    gn_partial<<<dim3(64, NB), 256, 0, stream>>>((const float4*)x, parts);
    gn_reduce<<<1, 128, 0, stream>>>(parts, stats);
    gn_apply<<<8192, 256, 0, stream>>>((const float4*)x, stats, gsc, gbi, hf);
    wcast_t<<<dim3(64, 2), 256, 0, stream>>>(wq, wk, bq, bk, wT, bcat);
    prep_w<<<64, 256, 0, stream>>>(wv, wo, wT + 2 * CCH * CCH);
    prep_b<<<1, 512, 0, stream>>>(bv, wo, bo, bpv);

    // fused QKV': [16384,512] @ [1536,512]^T (q scaled). 64x12 = 768 blocks.
    gemm256<128, 0><<<dim3(768, 1), 512, 0, stream>>>(
        hf, 512, 0, wT, 512, 0, qkv, 1536, 0, bcat, nullptr, 16384, 1536, 512, sscale);
    vtrans<<<dim3(512, NB), 256, 0, stream>>>(qkv, vt);
    // scores (bf16): per batch q @ k^T. 16x16 = 256 blocks x 4 batches.
    gemm256<256, 1><<<dim3(256, NB), 512, 0, stream>>>(
        qkv, 1536, (size_t)NTOK * 1536, qkv + 512, 1536, (size_t)NTOK * 1536,
        S_all, NTOK, (size_t)NTOK * NTOK, nullptr, nullptr, NTOK, NTOK, CCH, 0.f);
    softmax_rows_bf16<<<dim3(NTOK, NB), 256, 0, stream>>>(S_all);
    // out = x + P @ V' + bpv (final, f32). 16x4 = 64 blocks x 4 batches.
    gemm256<128, 2><<<dim3(64, NB), 512, 0, stream>>>(
        S_all, NTOK, (size_t)NTOK * NTOK, vt, NTOK, (size_t)CCH * NTOK,
        out, CCH, (size_t)NTOK * CCH, bpv, x, NTOK, CCH, NTOK, 0.f);
  } else {
    // fallback (per-batch S): S1[33.6M] | qkv[50.3M] | vt[16.8M] | wT | extras
    bf16*  S1    = (bf16*)(ws + 0);
    bf16*  hf    = (bf16*)(ws + 0);
    bf16*  qkv   = (bf16*)(ws + 33554432);
    bf16*  vt    = (bf16*)(ws + 83886080);
    bf16*  wT    = (bf16*)(ws + 100663296);
    float* bpv   = (float*)(ws + 102236160);
    float* bcat  = (float*)(ws + 102760448);
    float* stats = (float*)(ws + 102766592);
    float* parts = (float*)(ws + 102767616);

    gn_partial<<<dim3(64, NB), 256, 0, stream>>>((const float4*)x, parts);
    gn_reduce<<<1, 128, 0, stream>>>(parts, stats);
    gn_apply<<<8192, 256, 0, stream>>>((const float4*)x, stats, gsc, gbi, hf);
    wcast_t<<<dim3(64, 2), 256, 0, stream>>>(wq, wk, bq, bk, wT, bcat);
    prep_w<<<64, 256, 0, stream>>>(wv, wo, wT + 2 * CCH * CCH);
    prep_b<<<1, 512, 0, stream>>>(bv, wo, bo, bpv);
    gemm256<128, 0><<<dim3(768, 1), 512, 0, stream>>>(
        hf, 512, 0, wT, 512, 0, qkv, 1536, 0, bcat, nullptr, 16384, 1536, 512, sscale);
    vtrans<<<dim3(512, NB), 256, 0, stream>>>(qkv, vt);
    for (int b = 0; b < NB; ++b) {
      const bf16* qb = qkv + (size_t)b * NTOK * 1536;
      gemm256<256, 1><<<dim3(256, 1), 512, 0, stream>>>(
          qb, 1536, 0, qb + 512, 1536, 0, S1, NTOK, 0, nullptr, nullptr,
          NTOK, NTOK, CCH, 0.f);
      softmax_rows_bf16<<<dim3(NTOK, 1), 256, 0, stream>>>(S1);
      gemm256<128, 2><<<dim3(64, 1), 512, 0, stream>>>(
          S1, NTOK, 0, vt + (size_t)b * CCH * NTOK, NTOK, 0,
          out + (size_t)b * NTOK * CCH, CCH, 0, bpv, x + (size_t)b * NTOK * CCH,
          NTOK, CCH, NTOK, 0.f);
    }
  }
}

// Round 5
// 349.196 us; speedup vs baseline: 1.9728x; 1.0061x over previous
//
#include <hip/hip_runtime.h>
#include <hip/hip_bf16.h>
#include <math.h>

// ---------------------------------------------------------------------------
// FlaxLTX2AudioAttnBlock: GN -> QKV proj -> softmax(QK^T/sqrt(C)) V -> proj -> +x
// B=4, N=4096 tokens/batch, C=512, G=32 groups.
// R5: 4-phase merged schedule (A-shared quadrant pairs, B-frags resident in
//     regs -> B read once per K-tile, barriers halved). Counted vmcnt
//     unchanged (re-derived). prep_b folded into prep_w.
// ---------------------------------------------------------------------------

typedef __bf16 bf16;
typedef float f32x4 __attribute__((ext_vector_type(4)));
typedef __bf16 bf16x8 __attribute__((ext_vector_type(8)));
typedef __bf16 bf16x4 __attribute__((ext_vector_type(4)));

#define AS1 __attribute__((address_space(1)))
#define AS3 __attribute__((address_space(3)))

#define NB   4
#define NTOK 4096
#define CCH  512
#define NGRP 32

__device__ __forceinline__ void gload_lds16(const void* g, void* l) {
  __builtin_amdgcn_global_load_lds((AS1 void*)(g), (AS3 void*)(l), 16, 0, 0);
}

// ---------------- GroupNorm stage 1: partial sums ---------------------------
__global__ __launch_bounds__(256) void gn_partial(const float4* __restrict__ x4,
                                                  float* __restrict__ partials) {
  const int chunk = blockIdx.x, b = blockIdx.y;
  const int tid = threadIdx.x;
  const size_t base = ((size_t)b * NTOK + (size_t)chunk * 64) * 128;  // float4s
  float s = 0.f, ss = 0.f;
  #pragma unroll 4
  for (int it = 0; it < 32; ++it) {
    const float4 v = x4[base + it * 256 + tid];
    s  += v.x + v.y + v.z + v.w;
    ss += v.x * v.x + v.y * v.y + v.z * v.z + v.w * v.w;
  }
  __shared__ float ls[256], lss[256];
  ls[tid] = s; lss[tid] = ss;
  __syncthreads();
  if (tid < 32) {
    float ps = 0.f, pss = 0.f;
    #pragma unroll
    for (int j = 0; j < 4; ++j) {
      ps  += ls[tid * 4 + j] + ls[128 + tid * 4 + j];
      pss += lss[tid * 4 + j] + lss[128 + tid * 4 + j];
    }
    const size_t o = (((size_t)b * 64 + chunk) * 32 + tid) * 2;
    partials[o] = ps; partials[o + 1] = pss;
  }
}

// ---------------- GroupNorm stage 2: reduce 64 chunks -> stats --------------
__global__ __launch_bounds__(128) void gn_reduce(const float* __restrict__ partials,
                                                 float* __restrict__ stats) {
  const int tid = threadIdx.x;          // tid = b*32 + g
  const int b = tid >> 5, g = tid & 31;
  float s = 0.f, ss = 0.f;
  for (int c = 0; c < 64; ++c) {
    const size_t o = (((size_t)b * 64 + c) * 32 + g) * 2;
    s += partials[o]; ss += partials[o + 1];
  }
  const float inv = 1.f / (NTOK * 16.f);
  const float mean = s * inv;
  const float var = ss * inv - mean * mean;
  stats[tid * 2] = mean;
  stats[tid * 2 + 1] = rsqrtf(var + 1e-6f);
}

// ---------------- normalize + affine + cast to bf16 -------------------------
__global__ __launch_bounds__(256) void gn_apply(const float4* __restrict__ x4,
                                                const float* __restrict__ stats,
                                                const float* __restrict__ gsc,
                                                const float* __restrict__ gbi,
                                                bf16* __restrict__ hf) {
  const int i = blockIdx.x * 256 + threadIdx.x;   // over 2,097,152 float4s
  const float4 v = x4[i];
  const size_t e = (size_t)i * 4;
  const int c = (int)(e & (CCH - 1));
  const int b = (int)(e >> 21);
  const int g = c >> 4;
  const float mean = stats[(b * NGRP + g) * 2];
  const float rstd = stats[(b * NGRP + g) * 2 + 1];
  bf16x4 o;
  o[0] = (bf16)((v.x - mean) * rstd * gsc[c + 0] + gbi[c + 0]);
  o[1] = (bf16)((v.y - mean) * rstd * gsc[c + 1] + gbi[c + 1]);
  o[2] = (bf16)((v.z - mean) * rstd * gsc[c + 2] + gbi[c + 2]);
  o[3] = (bf16)((v.w - mean) * rstd * gsc[c + 3] + gbi[c + 3]);
  *reinterpret_cast<bf16x4*>(&hf[e]) = o;
}

// ---------------- weight transpose+cast (wq, wk) + bias concat --------------
__global__ __launch_bounds__(256) void wcast_t(const float* __restrict__ wq,
                                               const float* __restrict__ wk,
                                               const float* __restrict__ bq,
                                               const float* __restrict__ bk,
                                               bf16* __restrict__ dst,
                                               float* __restrict__ bcat) {
  const int w = blockIdx.y;                // 0 = wq, 1 = wk
  const float* src = (w == 0) ? wq : wk;
  bf16* out = dst + (size_t)w * CCH * CCH;
  const int t = blockIdx.x;                // 8x8 tiles of 64x64
  const int tr = t >> 3, tc = t & 7;
  if (t == 0) {
    const float* bsrc = (w == 0) ? bq : bk;
    for (int i = threadIdx.x; i < CCH; i += 256) {
      bcat[w * CCH + i] = bsrc[i];
      if (w == 0) bcat[2 * CCH + i] = 0.f;   // v' bias folded into bpv
    }
  }
  __shared__ float tile[64][65];
  for (int i = threadIdx.x; i < 4096; i += 256) {
    const int r = i >> 6, c = i & 63;
    tile[r][c] = src[(size_t)(tr * 64 + r) * CCH + tc * 64 + c];
  }
  __syncthreads();
  for (int i = threadIdx.x; i < 4096; i += 256) {
    const int r = i >> 6, c = i & 63;
    out[(size_t)(tc * 64 + r) * CCH + tr * 64 + c] = (bf16)tile[c][r];
  }
}

// ---------------- prep: W'^T = (wv@wo)^T bf16; block 0 also bpv -------------
__global__ __launch_bounds__(256) void prep_w(const float* __restrict__ wv,
                                              const float* __restrict__ wo,
                                              const float* __restrict__ bv,
                                              const float* __restrict__ bo,
                                              bf16* __restrict__ wpT,
                                              float* __restrict__ bpv) {
  const int ta = blockIdx.x >> 3, tb = blockIdx.x & 7;   // 8x8 blocks of 64x64
  __shared__ float woS[64][65];   // [kk][aa]
  __shared__ float wvS[64][65];   // [bb][kk]
  const int t = threadIdx.x;
  if (blockIdx.x == 0) {           // bpv = bv @ wo + bo
    for (int j = t; j < CCH; j += 256) {
      float a2 = bo[j];
      for (int k2 = 0; k2 < CCH; ++k2) a2 += bv[k2] * wo[(size_t)k2 * CCH + j];
      bpv[j] = a2;
    }
  }
  const int aa0 = (t & 15) * 4, bb0 = (t >> 4) * 4;
  float acc[4][4] = {};
  for (int kt = 0; kt < CCH; kt += 64) {
    for (int i = t; i < 4096; i += 256) {
      const int r = i >> 6, c = i & 63;
      woS[r][c] = wo[(size_t)(kt + r) * CCH + ta * 64 + c];
      wvS[r][c] = wv[(size_t)(tb * 64 + r) * CCH + kt + c];
    }
    __syncthreads();
    #pragma unroll 8
    for (int kk = 0; kk < 64; ++kk) {
      float wo4[4], wv4[4];
      #pragma unroll
      for (int i2 = 0; i2 < 4; ++i2) { wo4[i2] = woS[kk][aa0 + i2]; wv4[i2] = wvS[bb0 + i2][kk]; }
      #pragma unroll
      for (int a2 = 0; a2 < 4; ++a2)
        #pragma unroll
        for (int b2 = 0; b2 < 4; ++b2)
          acc[a2][b2] += wo4[a2] * wv4[b2];
    }
    __syncthreads();
  }
  #pragma unroll
  for (int a2 = 0; a2 < 4; ++a2)
    #pragma unroll
    for (int b2 = 0; b2 < 4; ++b2)
      wpT[(size_t)(ta * 64 + aa0 + a2) * CCH + tb * 64 + bb0 + b2] = (bf16)acc[a2][b2];
}

// ---------------- bf16 transpose: qkv v'-cols [tok][1536] -> vt[d][tok] -----
__global__ __launch_bounds__(256) void vtrans(const bf16* __restrict__ qkv,
                                              bf16* __restrict__ vt) {
  const int b = blockIdx.y;
  const bf16* src = qkv + (size_t)b * NTOK * 1536 + 1024;   // v' columns
  bf16* out = vt + (size_t)b * CCH * NTOK;
  const int t = blockIdx.x;                // 64x8 tiles of 64x64
  const int tr = t >> 3, tc = t & 7;
  __shared__ bf16 tile[64][65];
  for (int i = threadIdx.x; i < 4096; i += 256) {
    const int r = i >> 6, c = i & 63;
    tile[r][c] = src[(size_t)(tr * 64 + r) * 1536 + tc * 64 + c];
  }
  __syncthreads();
  for (int i = threadIdx.x; i < 4096; i += 256) {
    const int r = i >> 6, c = i & 63;
    out[(size_t)(tc * 64 + r) * NTOK + tr * 64 + c] = tile[c][r];
  }
}

// ---------------- row softmax, bf16 in-place --------------------------------
__global__ __launch_bounds__(256) void softmax_rows_bf16(bf16* __restrict__ Sall) {
  const size_t row = (size_t)blockIdx.y * NTOK + blockIdx.x;
  bf16* p = Sall + row * NTOK;
  const int tid = threadIdx.x, lane = tid & 63, wave = tid >> 6;
  const bf16x8 a = ((const bf16x8*)p)[tid];
  const bf16x8 b2 = ((const bf16x8*)p)[256 + tid];
  float v[16];
  float m = -1e30f;
  #pragma unroll
  for (int j = 0; j < 8; ++j) { v[j] = (float)a[j]; v[8 + j] = (float)b2[j]; }
  #pragma unroll
  for (int j = 0; j < 16; ++j) m = fmaxf(m, v[j]);
  #pragma unroll
  for (int off = 32; off > 0; off >>= 1) m = fmaxf(m, __shfl_xor(m, off));
  __shared__ float redm[4], redsum[4];
  if (lane == 0) redm[wave] = m;
  __syncthreads();
  m = fmaxf(fmaxf(redm[0], redm[1]), fmaxf(redm[2], redm[3]));
  float sum = 0.f;
  #pragma unroll
  for (int j = 0; j < 16; ++j) { v[j] = __expf(v[j] - m); sum += v[j]; }
  #pragma unroll
  for (int off = 32; off > 0; off >>= 1) sum += __shfl_xor(sum, off);
  if (lane == 0) redsum[wave] = sum;
  __syncthreads();
  sum = redsum[0] + redsum[1] + redsum[2] + redsum[3];
  const float r = 1.f / sum;
  bf16x8 oa, ob;
  #pragma unroll
  for (int j = 0; j < 8; ++j) { oa[j] = (bf16)(v[j] * r); ob[j] = (bf16)(v[8 + j] * r); }
  ((bf16x8*)p)[tid] = oa;
  ((bf16x8*)p)[256 + tid] = ob;
}

// ---------------- 4-phase 256xBN MFMA GEMM: C = A @ Bt^T (+ epilogue) -------
// 512 threads = 8 waves (2M x 4N). BM=256, BNt in {256,128}, BK=64.
// Per phase: {ds_read (A-half; B all frags once per K-tile) || 2 stage-issues
// -> barrier -> lgkmcnt(0) -> 32/16-MFMA setprio cluster -> barrier}.
// B-frags stay resident in regs across the phase pair (B read once/K-tile).
// Stage slots = 8-phase template merged pairwise; counted-vmcnt identical:
//   P2: VMW(SS) drains prev-P4 + P1 stages  => buf for P3 ready
//   P4: VMW(SS) drains P2 + P3 stages       => buf for next-P1 ready
//   SS = loads/phase = 4 (BN=256) or 3 (BN=128)
// EPI: 0 = +bias, *scale on cols<CCH, bf16 out (QKV) | 1 = plain bf16 out
//      (scores) | 2 = +bias +residual, f32 out (PV -> final output)
template <int BNt, int EPI>
__global__ __launch_bounds__(512, 2) void gemm256(
    const bf16* __restrict__ A, int lda, size_t sA,
    const bf16* __restrict__ Bt, int ldb, size_t sB,
    void* __restrict__ C, int ldc, size_t sC,
    const float* __restrict__ bias, const float* __restrict__ resid,
    int M, int N, int K, float scale) {
  constexpr int BK = 64;
  constexpr int WN = BNt / 4;        // per-wave N extent (64 or 32)
  constexpr int NREP = WN / 16;      // N fragments per wave (4 or 2)
  constexpr int BH = BNt / 2;        // B half-tile rows (128 or 64)
  constexpr int BISS = BNt / 128;    // gload issues per B half (2 or 1)

  __shared__ bf16 Al[2][256 * BK];
  __shared__ bf16 Bl[2][BNt * BK];

  A += (size_t)blockIdx.y * sA;
  Bt += (size_t)blockIdx.y * sB;

  const int tid = threadIdx.x;
  const int lane = tid & 63;
  const int wave = tid >> 6;
  const int wm = wave >> 2, wn = wave & 3;
  const int fr = lane & 15, fq = lane >> 4;
  const int nbn = N / BNt;
  int bx = blockIdx.x;
  const int nwg = gridDim.x;
  bx = (bx & 7) * (nwg >> 3) + (bx >> 3);    // XCD swizzle (all grids %8==0)
  const int bm = bx / nbn, bn = bx % nbn;

  // staging: thread covers 16B chunk; T2: global chunk = lds chunk ^ (row&7)
  const int srow = tid >> 3;                              // 0..63
  const int scol = (((tid & 7) ^ (srow & 7)) * 8);
  const bf16* Ab = A + (size_t)(bm * 256 + srow) * lda + scol;
  const bf16* Bb = Bt + (size_t)(bn * BNt + srow) * ldb + scol;

  // swizzled ds_read chunk offsets (elems): chunk (ks*4+fq) ^ (fr&7)
  const int xk = fr & 7;
  const int c0 = ((0 + fq) ^ xk) * 8;
  const int c1 = ((4 + fq) ^ xk) * 8;
  const int aroff = (wm * 128 + fr) * BK;
  const int broff = (wn * WN + fr) * BK;

  f32x4 acc[8][NREP];
  #pragma unroll
  for (int m2 = 0; m2 < 8; ++m2)
    #pragma unroll
    for (int n2 = 0; n2 < NREP; ++n2)
      acc[m2][n2] = f32x4{0.f, 0.f, 0.f, 0.f};
  bf16x8 af[4][2];
  bf16x8 bfr[NREP][2];

#define STAGE_A(buf, h, kt)                                                     \
  { gload_lds16(Ab + (size_t)((h) * 128) * lda + (kt),                          \
                &Al[buf][(h) * 8192 + wave * 512]);                             \
    gload_lds16(Ab + (size_t)((h) * 128 + 64) * lda + (kt),                     \
                &Al[buf][(h) * 8192 + 4096 + wave * 512]); }
#define STAGE_B(buf, h, kt)                                                     \
  { gload_lds16(Bb + (size_t)((h) * BH) * ldb + (kt),                           \
                &Bl[buf][(h) * BH * BK + wave * 512]);                          \
    if (BISS == 2)                                                              \
      gload_lds16(Bb + (size_t)((h) * BH + 64) * ldb + (kt),                    \
                  &Bl[buf][(h) * BH * BK + 4096 + wave * 512]); }
#define LOADA(buf, mh)                                                          \
  { _Pragma("unroll") for (int mi = 0; mi < 4; ++mi) {                          \
      af[mi][0] = *(const bf16x8*)&Al[buf][aroff + ((mh) * 64 + mi * 16) * BK + c0]; \
      af[mi][1] = *(const bf16x8*)&Al[buf][aroff + ((mh) * 64 + mi * 16) * BK + c1]; } }
#define LOADB(buf)                                                              \
  { _Pragma("unroll") for (int ni = 0; ni < NREP; ++ni) {                       \
      bfr[ni][0] = *(const bf16x8*)&Bl[buf][broff + (ni * 16) * BK + c0];       \
      bfr[ni][1] = *(const bf16x8*)&Bl[buf][broff + (ni * 16) * BK + c1]; } }
#define MMA(mh)                                                                 \
  { __builtin_amdgcn_s_setprio(1);                                              \
    _Pragma("unroll") for (int mi = 0; mi < 4; ++mi)                            \
      _Pragma("unroll") for (int ni = 0; ni < NREP; ++ni) {                     \
        acc[(mh) * 4 + mi][ni] = __builtin_amdgcn_mfma_f32_16x16x32_bf16(       \
            af[mi][0], bfr[ni][0], acc[(mh) * 4 + mi][ni], 0, 0, 0);            \
        acc[(mh) * 4 + mi][ni] = __builtin_amdgcn_mfma_f32_16x16x32_bf16(       \
            af[mi][1], bfr[ni][1], acc[(mh) * 4 + mi][ni], 0, 0, 0); }          \
    __builtin_amdgcn_s_setprio(0); }
#define BARX() __builtin_amdgcn_s_barrier()
#define PIN() __builtin_amdgcn_sched_barrier(0)
#define LGKM0() { asm volatile("s_waitcnt lgkmcnt(0)" ::: "memory"); PIN(); }
#define VMW(n) asm volatile("s_waitcnt vmcnt(" #n ")" ::: "memory")
#define VMWSS() { if (BISS == 2) VMW(4); else VMW(3); }   // steady-state count

  // prologue: tile0 (4 halves) + A0,B0 of tile1 -> keep 2 halves in flight
  STAGE_A(0, 0, 0); STAGE_A(0, 1, 0);
  STAGE_B(0, 0, 0); STAGE_B(0, 1, 0);
  STAGE_A(1, 0, BK); STAGE_B(1, 0, BK);
  VMWSS();
  BARX();

  const int niter = K >> 7;      // 2 K-tiles (BK=64) per iteration
  for (int j = 0; j < niter; ++j) {
    const int kt1 = j * 128 + 64;
    const int kt2 = kt1 + 64, kt3 = kt1 + 128;
    const bool last = (j == niter - 1);
    // P1: tile t (buf0) mh=0 + B-all; stage A1(t+1),B1(t+1)->buf1
    LOADA(0, 0); LOADB(0); STAGE_A(1, 1, kt1); STAGE_B(1, 1, kt1);
    PIN(); BARX(); LGKM0(); MMA(0); BARX();
    // P2: mh=1 (B resident); stage A0(t+2),B0(t+2)->buf0; counted vmcnt
    LOADA(0, 1); if (!last) { STAGE_A(0, 0, kt2); STAGE_B(0, 0, kt2); }
    PIN(); BARX(); LGKM0(); MMA(1);
    if (last) { VMW(0); } else VMWSS();
    BARX();
    // P3: tile t+1 (buf1) mh=0 + B-all; stage A1(t+2),B1(t+2)->buf0
    LOADA(1, 0); LOADB(1); if (!last) { STAGE_A(0, 1, kt2); STAGE_B(0, 1, kt2); }
    PIN(); BARX(); LGKM0(); MMA(0); BARX();
    // P4: mh=1; stage A0(t+3),B0(t+3)->buf1; counted vmcnt
    LOADA(1, 1); if (!last) { STAGE_A(1, 0, kt3); STAGE_B(1, 0, kt3); }
    PIN(); BARX(); LGKM0(); MMA(1);
    if (!last) VMWSS();
    BARX();
  }

  // epilogue
  const int crow0 = bm * 256 + wm * 128 + fq * 4;
  const int ccol0 = bn * BNt + wn * WN + fr;
  #pragma unroll
  for (int mh = 0; mh < 2; ++mh)
    #pragma unroll
    for (int mi = 0; mi < 4; ++mi)
      #pragma unroll
      for (int nr = 0; nr < NREP; ++nr)
        #pragma unroll
        for (int jj = 0; jj < 4; ++jj) {
          const int row = crow0 + mh * 64 + mi * 16 + jj;
          const int col = ccol0 + nr * 16;
          const float val = acc[mh * 4 + mi][nr][jj];
          const size_t idx = (size_t)row * ldc + col;
          if constexpr (EPI == 0) {
            float vv = val + bias[col];
            if (col < CCH) vv *= scale;
            ((bf16*)C)[(size_t)blockIdx.y * sC + idx] = (bf16)vv;
          } else if constexpr (EPI == 1) {
            ((bf16*)C)[(size_t)blockIdx.y * sC + idx] = (bf16)val;
          } else {
            float* Cf = (float*)C + (size_t)blockIdx.y * sC;
            Cf[idx] = val + bias[col] + resid[(size_t)blockIdx.y * sC + idx];
          }
        }
#undef STAGE_A
#undef STAGE_B
#undef LOADA
#undef LOADB
#undef MMA
#undef BARX
#undef PIN
#undef LGKM0
#undef VMW
#undef VMWSS
}

// ---------------------------------------------------------------------------
extern "C" void kernel_launch(void* const* d_in, const int* in_sizes, int n_in,
                              void* d_out, int out_size, void* d_ws, size_t ws_size,
                              hipStream_t stream) {
  const float* x   = (const float*)d_in[0];
  const float* gsc = (const float*)d_in[1];
  const float* gbi = (const float*)d_in[2];
  const float* wq  = (const float*)d_in[3];
  const float* bq  = (const float*)d_in[4];
  const float* wk  = (const float*)d_in[5];
  const float* bk  = (const float*)d_in[6];
  const float* wv  = (const float*)d_in[7];
  const float* bv  = (const float*)d_in[8];
  const float* wo  = (const float*)d_in[9];
  const float* bo  = (const float*)d_in[10];
  float* out = (float*)d_out;
  char* ws = (char*)d_ws;

  const float sscale = 0.044194173824159216f;  // 1/sqrt(512)
  const bool batched = ws_size >= 203496448ULL;

  if (batched) {
    // S_all[134.2M] | qkv[50.3M] | vt[16.8M] | wT[2.1M incl W'T] | extras
    bf16*  S_all = (bf16*)(ws + 0);
    bf16*  hf    = (bf16*)(ws + 0);             // alias: dead before S written
    bf16*  qkv   = (bf16*)(ws + 134217728);
    bf16*  vt    = (bf16*)(ws + 184549376);
    bf16*  wT    = (bf16*)(ws + 201326592);     // slots: wqT | wkT | W'T | free
    float* bpv   = (float*)(ws + 202899456);    // in unused slot 3
    float* bcat  = (float*)(ws + 203423744);
    float* stats = (float*)(ws + 203429888);
    float* parts = (float*)(ws + 203430912);

    gn_partial<<<dim3(64, NB), 256, 0, stream>>>((const float4*)x, parts);
    gn_reduce<<<1, 128, 0, stream>>>(parts, stats);
    gn_apply<<<8192, 256, 0, stream>>>((const float4*)x, stats, gsc, gbi, hf);
    wcast_t<<<dim3(64, 2), 256, 0, stream>>>(wq, wk, bq, bk, wT, bcat);
    prep_w<<<64, 256, 0, stream>>>(wv, wo, bv, bo, wT + 2 * CCH * CCH, bpv);

    // fused QKV': [16384,512] @ [1536,512]^T (q scaled). 64x12 = 768 blocks.
    gemm256<128, 0><<<dim3(768, 1), 512, 0, stream>>>(
        hf, 512, 0, wT, 512, 0, qkv, 1536, 0, bcat, nullptr, 16384, 1536, 512, sscale);
    vtrans<<<dim3(512, NB), 256, 0, stream>>>(qkv, vt);
    // scores (bf16): per batch q @ k^T. 16x16 = 256 blocks x 4 batches.
    gemm256<256, 1><<<dim3(256, NB), 512, 0, stream>>>(
        qkv, 1536, (size_t)NTOK * 1536, qkv + 512, 1536, (size_t)NTOK * 1536,
        S_all, NTOK, (size_t)NTOK * NTOK, nullptr, nullptr, NTOK, NTOK, CCH, 0.f);
    softmax_rows_bf16<<<dim3(NTOK, NB), 256, 0, stream>>>(S_all);
    // out = x + P @ V' + bpv (final, f32). 16x4 = 64 blocks x 4 batches.
    gemm256<128, 2><<<dim3(64, NB), 512, 0, stream>>>(
        S_all, NTOK, (size_t)NTOK * NTOK, vt, NTOK, (size_t)CCH * NTOK,
        out, CCH, (size_t)NTOK * CCH, bpv, x, NTOK, CCH, NTOK, 0.f);
  } else {
    // fallback (per-batch S): S1[33.6M] | qkv[50.3M] | vt[16.8M] | wT | extras
    bf16*  S1    = (bf16*)(ws + 0);
    bf16*  hf    = (bf16*)(ws + 0);
    bf16*  qkv   = (bf16*)(ws + 33554432);
    bf16*  vt    = (bf16*)(ws + 83886080);
    bf16*  wT    = (bf16*)(ws + 100663296);
    float* bpv   = (float*)(ws + 102236160);
    float* bcat  = (float*)(ws + 102760448);
    float* stats = (float*)(ws + 102766592);
    float* parts = (float*)(ws + 102767616);

    gn_partial<<<dim3(64, NB), 256, 0, stream>>>((const float4*)x, parts);
    gn_reduce<<<1, 128, 0, stream>>>(parts, stats);
    gn_apply<<<8192, 256, 0, stream>>>((const float4*)x, stats, gsc, gbi, hf);
    wcast_t<<<dim3(64, 2), 256, 0, stream>>>(wq, wk, bq, bk, wT, bcat);
    prep_w<<<64, 256, 0, stream>>>(wv, wo, bv, bo, wT + 2 * CCH * CCH, bpv);
    gemm256<128, 0><<<dim3(768, 1), 512, 0, stream>>>(
        hf, 512, 0, wT, 512, 0, qkv, 1536, 0, bcat, nullptr, 16384, 1536, 512, sscale);
    vtrans<<<dim3(512, NB), 256, 0, stream>>>(qkv, vt);
    for (int b = 0; b < NB; ++b) {
      const bf16* qb = qkv + (size_t)b * NTOK * 1536;
      gemm256<256, 1><<<dim3(256, 1), 512, 0, stream>>>(
          qb, 1536, 0, qb + 512, 1536, 0, S1, NTOK, 0, nullptr, nullptr,
          NTOK, NTOK, CCH, 0.f);
      softmax_rows_bf16<<<dim3(NTOK, 1), 256, 0, stream>>>(S1);
      gemm256<128, 2><<<dim3(64, 1), 512, 0, stream>>>(
          S1, NTOK, 0, vt + (size_t)b * CCH * NTOK, NTOK, 0,
          out + (size_t)b * NTOK * CCH, CCH, 0, bpv, x + (size_t)b * NTOK * CCH,
          NTOK, CCH, NTOK, 0.f);
    }
  }
}

// Round 6
// 319.938 us; speedup vs baseline: 2.1532x; 1.0914x over previous
//
#include <hip/hip_runtime.h>
#include <hip/hip_bf16.h>
#include <math.h>

// ---------------------------------------------------------------------------
// FlaxLTX2AudioAttnBlock: GN -> QKV proj -> softmax(QK^T/sqrt(C)) V -> proj -> +x
// B=4, N=4096 tokens/batch, C=512, G=32 groups.
// R6: softmax kernel eliminated (exp in scores epilogue + deterministic
//     per-block row-sum partials + 1/sum folded into PV epilogue);
//     vtrans eliminated (V'^T computed directly as a GEMM: A=W'^T, Bt=hf);
//     QKV proj shrunk to QK-only. 4-phase gemm256 schedule unchanged.
// ---------------------------------------------------------------------------

typedef __bf16 bf16;
typedef float f32x4 __attribute__((ext_vector_type(4)));
typedef __bf16 bf16x8 __attribute__((ext_vector_type(8)));
typedef __bf16 bf16x4 __attribute__((ext_vector_type(4)));

#define AS1 __attribute__((address_space(1)))
#define AS3 __attribute__((address_space(3)))

#define NB   4
#define NTOK 4096
#define CCH  512
#define NGRP 32

__device__ __forceinline__ void gload_lds16(const void* g, void* l) {
  __builtin_amdgcn_global_load_lds((AS1 void*)(g), (AS3 void*)(l), 16, 0, 0);
}

// ---------------- GroupNorm stage 1: partial sums ---------------------------
__global__ __launch_bounds__(256) void gn_partial(const float4* __restrict__ x4,
                                                  float* __restrict__ partials) {
  const int chunk = blockIdx.x, b = blockIdx.y;
  const int tid = threadIdx.x;
  const size_t base = ((size_t)b * NTOK + (size_t)chunk * 64) * 128;  // float4s
  float s = 0.f, ss = 0.f;
  #pragma unroll 4
  for (int it = 0; it < 32; ++it) {
    const float4 v = x4[base + it * 256 + tid];
    s  += v.x + v.y + v.z + v.w;
    ss += v.x * v.x + v.y * v.y + v.z * v.z + v.w * v.w;
  }
  __shared__ float ls[256], lss[256];
  ls[tid] = s; lss[tid] = ss;
  __syncthreads();
  if (tid < 32) {
    float ps = 0.f, pss = 0.f;
    #pragma unroll
    for (int j = 0; j < 4; ++j) {
      ps  += ls[tid * 4 + j] + ls[128 + tid * 4 + j];
      pss += lss[tid * 4 + j] + lss[128 + tid * 4 + j];
    }
    const size_t o = (((size_t)b * 64 + chunk) * 32 + tid) * 2;
    partials[o] = ps; partials[o + 1] = pss;
  }
}

// ---------------- GroupNorm stage 2: reduce 64 chunks -> stats --------------
__global__ __launch_bounds__(128) void gn_reduce(const float* __restrict__ partials,
                                                 float* __restrict__ stats) {
  const int tid = threadIdx.x;          // tid = b*32 + g
  const int b = tid >> 5, g = tid & 31;
  float s = 0.f, ss = 0.f;
  for (int c = 0; c < 64; ++c) {
    const size_t o = (((size_t)b * 64 + c) * 32 + g) * 2;
    s += partials[o]; ss += partials[o + 1];
  }
  const float inv = 1.f / (NTOK * 16.f);
  const float mean = s * inv;
  const float var = ss * inv - mean * mean;
  stats[tid * 2] = mean;
  stats[tid * 2 + 1] = rsqrtf(var + 1e-6f);
}

// ---------------- normalize + affine + cast to bf16 -------------------------
__global__ __launch_bounds__(256) void gn_apply(const float4* __restrict__ x4,
                                                const float* __restrict__ stats,
                                                const float* __restrict__ gsc,
                                                const float* __restrict__ gbi,
                                                bf16* __restrict__ hf) {
  const int i = blockIdx.x * 256 + threadIdx.x;   // over 2,097,152 float4s
  const float4 v = x4[i];
  const size_t e = (size_t)i * 4;
  const int c = (int)(e & (CCH - 1));
  const int b = (int)(e >> 21);
  const int g = c >> 4;
  const float mean = stats[(b * NGRP + g) * 2];
  const float rstd = stats[(b * NGRP + g) * 2 + 1];
  bf16x4 o;
  o[0] = (bf16)((v.x - mean) * rstd * gsc[c + 0] + gbi[c + 0]);
  o[1] = (bf16)((v.y - mean) * rstd * gsc[c + 1] + gbi[c + 1]);
  o[2] = (bf16)((v.z - mean) * rstd * gsc[c + 2] + gbi[c + 2]);
  o[3] = (bf16)((v.w - mean) * rstd * gsc[c + 3] + gbi[c + 3]);
  *reinterpret_cast<bf16x4*>(&hf[e]) = o;
}

// ---------------- weight transpose+cast (wq, wk) + bias concat --------------
__global__ __launch_bounds__(256) void wcast_t(const float* __restrict__ wq,
                                               const float* __restrict__ wk,
                                               const float* __restrict__ bq,
                                               const float* __restrict__ bk,
                                               bf16* __restrict__ dst,
                                               float* __restrict__ bcat) {
  const int w = blockIdx.y;                // 0 = wq, 1 = wk
  const float* src = (w == 0) ? wq : wk;
  bf16* out = dst + (size_t)w * CCH * CCH;
  const int t = blockIdx.x;                // 8x8 tiles of 64x64
  const int tr = t >> 3, tc = t & 7;
  if (t == 0) {
    const float* bsrc = (w == 0) ? bq : bk;
    for (int i = threadIdx.x; i < CCH; i += 256) bcat[w * CCH + i] = bsrc[i];
  }
  __shared__ float tile[64][65];
  for (int i = threadIdx.x; i < 4096; i += 256) {
    const int r = i >> 6, c = i & 63;
    tile[r][c] = src[(size_t)(tr * 64 + r) * CCH + tc * 64 + c];
  }
  __syncthreads();
  for (int i = threadIdx.x; i < 4096; i += 256) {
    const int r = i >> 6, c = i & 63;
    out[(size_t)(tc * 64 + r) * CCH + tr * 64 + c] = (bf16)tile[c][r];
  }
}

// ---------------- prep: W'^T = (wv@wo)^T bf16; block 0 also bpv -------------
__global__ __launch_bounds__(256) void prep_w(const float* __restrict__ wv,
                                              const float* __restrict__ wo,
                                              const float* __restrict__ bv,
                                              const float* __restrict__ bo,
                                              bf16* __restrict__ wpT,
                                              float* __restrict__ bpv) {
  const int ta = blockIdx.x >> 3, tb = blockIdx.x & 7;   // 8x8 blocks of 64x64
  __shared__ float woS[64][65];   // [kk][aa]
  __shared__ float wvS[64][65];   // [bb][kk]
  const int t = threadIdx.x;
  if (blockIdx.x == 0) {           // bpv = bv @ wo + bo
    for (int j = t; j < CCH; j += 256) {
      float a2 = bo[j];
      for (int k2 = 0; k2 < CCH; ++k2) a2 += bv[k2] * wo[(size_t)k2 * CCH + j];
      bpv[j] = a2;
    }
  }
  const int aa0 = (t & 15) * 4, bb0 = (t >> 4) * 4;
  float acc[4][4] = {};
  for (int kt = 0; kt < CCH; kt += 64) {
    for (int i = t; i < 4096; i += 256) {
      const int r = i >> 6, c = i & 63;
      woS[r][c] = wo[(size_t)(kt + r) * CCH + ta * 64 + c];
      wvS[r][c] = wv[(size_t)(tb * 64 + r) * CCH + kt + c];
    }
    __syncthreads();
    #pragma unroll 8
    for (int kk = 0; kk < 64; ++kk) {
      float wo4[4], wv4[4];
      #pragma unroll
      for (int i2 = 0; i2 < 4; ++i2) { wo4[i2] = woS[kk][aa0 + i2]; wv4[i2] = wvS[bb0 + i2][kk]; }
      #pragma unroll
      for (int a2 = 0; a2 < 4; ++a2)
        #pragma unroll
        for (int b2 = 0; b2 < 4; ++b2)
          acc[a2][b2] += wo4[a2] * wv4[b2];
    }
    __syncthreads();
  }
  #pragma unroll
  for (int a2 = 0; a2 < 4; ++a2)
    #pragma unroll
    for (int b2 = 0; b2 < 4; ++b2)
      wpT[(size_t)(ta * 64 + aa0 + a2) * CCH + tb * 64 + bb0 + b2] = (bf16)acc[a2][b2];
}

// ---------------- row-sum reduce: partials[rows][16] -> rinv = 1/sum --------
__global__ __launch_bounds__(256) void rowsum_inv(const float* __restrict__ partials,
                                                  float* __restrict__ rinv) {
  const int row = blockIdx.x * 256 + threadIdx.x;
  const float* p = partials + (size_t)row * 16;
  float s = 0.f;
  #pragma unroll
  for (int j = 0; j < 16; ++j) s += p[j];
  rinv[row] = 1.f / s;
}

// ---------------- 4-phase 256xBN MFMA GEMM: C = A @ Bt^T (+ epilogue) -------
// 512 threads = 8 waves (2M x 4N). BM=256, BNt in {256,128}, BK=64.
// Schedule as R5 (4-phase merged, B-frags register-resident, counted vmcnt).
// EPI: 0 = +bias, *scale on cols<CCH, bf16 out (QK proj)
//      1 = exp(min(val,40)) bf16 out + per-block row-sum partials (scores)
//      2 = *rinv[row] +bias +resid, f32 out (PV -> final output)
//      3 = plain bf16 out (V'^T)
template <int BNt, int EPI>
__global__ __launch_bounds__(512, 2) void gemm256(
    const bf16* __restrict__ A, int lda, size_t sA,
    const bf16* __restrict__ Bt, int ldb, size_t sB,
    void* __restrict__ C, int ldc, size_t sC,
    const float* __restrict__ bias, const float* __restrict__ resid,
    float* __restrict__ partials, const float* __restrict__ rinv,
    int M, int N, int K, float scale) {
  constexpr int BK = 64;
  constexpr int WN = BNt / 4;        // per-wave N extent (64 or 32)
  constexpr int NREP = WN / 16;      // N fragments per wave (4 or 2)
  constexpr int BH = BNt / 2;        // B half-tile rows (128 or 64)
  constexpr int BISS = BNt / 128;    // gload issues per B half (2 or 1)

  __shared__ bf16 Al[2][256 * BK];
  __shared__ bf16 Bl[2][BNt * BK];

  A += (size_t)blockIdx.y * sA;
  Bt += (size_t)blockIdx.y * sB;

  const int tid = threadIdx.x;
  const int lane = tid & 63;
  const int wave = tid >> 6;
  const int wm = wave >> 2, wn = wave & 3;
  const int fr = lane & 15, fq = lane >> 4;
  const int nbn = N / BNt;
  int bx = blockIdx.x;
  const int nwg = gridDim.x;
  bx = (bx & 7) * (nwg >> 3) + (bx >> 3);    // XCD swizzle (all grids %8==0)
  const int bm = bx / nbn, bn = bx % nbn;

  // staging: thread covers 16B chunk; T2: global chunk = lds chunk ^ (row&7)
  const int srow = tid >> 3;                              // 0..63
  const int scol = (((tid & 7) ^ (srow & 7)) * 8);
  const bf16* Ab = A + (size_t)(bm * 256 + srow) * lda + scol;
  const bf16* Bb = Bt + (size_t)(bn * BNt + srow) * ldb + scol;

  // swizzled ds_read chunk offsets (elems): chunk (ks*4+fq) ^ (fr&7)
  const int xk = fr & 7;
  const int c0 = ((0 + fq) ^ xk) * 8;
  const int c1 = ((4 + fq) ^ xk) * 8;
  const int aroff = (wm * 128 + fr) * BK;
  const int broff = (wn * WN + fr) * BK;

  f32x4 acc[8][NREP];
  #pragma unroll
  for (int m2 = 0; m2 < 8; ++m2)
    #pragma unroll
    for (int n2 = 0; n2 < NREP; ++n2)
      acc[m2][n2] = f32x4{0.f, 0.f, 0.f, 0.f};
  bf16x8 af[4][2];
  bf16x8 bfr[NREP][2];

#define STAGE_A(buf, h, kt)                                                     \
  { gload_lds16(Ab + (size_t)((h) * 128) * lda + (kt),                          \
                &Al[buf][(h) * 8192 + wave * 512]);                             \
    gload_lds16(Ab + (size_t)((h) * 128 + 64) * lda + (kt),                     \
                &Al[buf][(h) * 8192 + 4096 + wave * 512]); }
#define STAGE_B(buf, h, kt)                                                     \
  { gload_lds16(Bb + (size_t)((h) * BH) * ldb + (kt),                           \
                &Bl[buf][(h) * BH * BK + wave * 512]);                          \
    if (BISS == 2)                                                              \
      gload_lds16(Bb + (size_t)((h) * BH + 64) * ldb + (kt),                    \
                  &Bl[buf][(h) * BH * BK + 4096 + wave * 512]); }
#define LOADA(buf, mh)                                                          \
  { _Pragma("unroll") for (int mi = 0; mi < 4; ++mi) {                          \
      af[mi][0] = *(const bf16x8*)&Al[buf][aroff + ((mh) * 64 + mi * 16) * BK + c0]; \
      af[mi][1] = *(const bf16x8*)&Al[buf][aroff + ((mh) * 64 + mi * 16) * BK + c1]; } }
#define LOADB(buf)                                                              \
  { _Pragma("unroll") for (int ni = 0; ni < NREP; ++ni) {                       \
      bfr[ni][0] = *(const bf16x8*)&Bl[buf][broff + (ni * 16) * BK + c0];       \
      bfr[ni][1] = *(const bf16x8*)&Bl[buf][broff + (ni * 16) * BK + c1]; } }
#define MMA(mh)                                                                 \
  { __builtin_amdgcn_s_setprio(1);                                              \
    _Pragma("unroll") for (int mi = 0; mi < 4; ++mi)                            \
      _Pragma("unroll") for (int ni = 0; ni < NREP; ++ni) {                     \
        acc[(mh) * 4 + mi][ni] = __builtin_amdgcn_mfma_f32_16x16x32_bf16(       \
            af[mi][0], bfr[ni][0], acc[(mh) * 4 + mi][ni], 0, 0, 0);            \
        acc[(mh) * 4 + mi][ni] = __builtin_amdgcn_mfma_f32_16x16x32_bf16(       \
            af[mi][1], bfr[ni][1], acc[(mh) * 4 + mi][ni], 0, 0, 0); }          \
    __builtin_amdgcn_s_setprio(0); }
#define BARX() __builtin_amdgcn_s_barrier()
#define PIN() __builtin_amdgcn_sched_barrier(0)
#define LGKM0() { asm volatile("s_waitcnt lgkmcnt(0)" ::: "memory"); PIN(); }
#define VMW(n) asm volatile("s_waitcnt vmcnt(" #n ")" ::: "memory")
#define VMWSS() { if (BISS == 2) VMW(4); else VMW(3); }   // steady-state count

  // prologue: tile0 (4 halves) + A0,B0 of tile1 -> keep 2 halves in flight
  STAGE_A(0, 0, 0); STAGE_A(0, 1, 0);
  STAGE_B(0, 0, 0); STAGE_B(0, 1, 0);
  STAGE_A(1, 0, BK); STAGE_B(1, 0, BK);
  VMWSS();
  BARX();

  const int niter = K >> 7;      // 2 K-tiles (BK=64) per iteration
  for (int j = 0; j < niter; ++j) {
    const int kt1 = j * 128 + 64;
    const int kt2 = kt1 + 64, kt3 = kt1 + 128;
    const bool last = (j == niter - 1);
    // P1: tile t (buf0) mh=0 + B-all; stage A1(t+1),B1(t+1)->buf1
    LOADA(0, 0); LOADB(0); STAGE_A(1, 1, kt1); STAGE_B(1, 1, kt1);
    PIN(); BARX(); LGKM0(); MMA(0); BARX();
    // P2: mh=1 (B resident); stage A0(t+2),B0(t+2)->buf0; counted vmcnt
    LOADA(0, 1); if (!last) { STAGE_A(0, 0, kt2); STAGE_B(0, 0, kt2); }
    PIN(); BARX(); LGKM0(); MMA(1);
    if (last) { VMW(0); } else VMWSS();
    BARX();
    // P3: tile t+1 (buf1) mh=0 + B-all; stage A1(t+2),B1(t+2)->buf0
    LOADA(1, 0); LOADB(1); if (!last) { STAGE_A(0, 1, kt2); STAGE_B(0, 1, kt2); }
    PIN(); BARX(); LGKM0(); MMA(0); BARX();
    // P4: mh=1; stage A0(t+3),B0(t+3)->buf1; counted vmcnt
    LOADA(1, 1); if (!last) { STAGE_A(1, 0, kt3); STAGE_B(1, 0, kt3); }
    PIN(); BARX(); LGKM0(); MMA(1);
    if (!last) VMWSS();
    BARX();
  }

  // epilogue
  const int crow0 = bm * 256 + wm * 128 + fq * 4;
  const int ccol0 = bn * BNt + wn * WN + fr;
  if constexpr (EPI == 1) {
    // scores: write exp(val) bf16 + deterministic per-block row-sum partials
    float* sums = (float*)&Al[0][0];            // 256 rows x 4 wn, reuse LDS
    #pragma unroll
    for (int mh = 0; mh < 2; ++mh)
      #pragma unroll
      for (int mi = 0; mi < 4; ++mi)
        #pragma unroll
        for (int jj = 0; jj < 4; ++jj) {
          const int row = crow0 + mh * 64 + mi * 16 + jj;
          float rs = 0.f;
          #pragma unroll
          for (int nr = 0; nr < NREP; ++nr) {
            const float e = __expf(fminf(acc[mh * 4 + mi][nr][jj], 40.f));
            rs += e;
            ((bf16*)C)[(size_t)blockIdx.y * sC + (size_t)row * ldc + ccol0 + nr * 16] = (bf16)e;
          }
          rs += __shfl_xor(rs, 1); rs += __shfl_xor(rs, 2);
          rs += __shfl_xor(rs, 4); rs += __shfl_xor(rs, 8);
          if (fr == 0)
            sums[(wm * 128 + mh * 64 + mi * 16 + fq * 4 + jj) * 4 + wn] = rs;
        }
    __syncthreads();
    if (tid < 256) {
      const float s4 = sums[tid * 4] + sums[tid * 4 + 1] +
                       sums[tid * 4 + 2] + sums[tid * 4 + 3];
      partials[((size_t)blockIdx.y * M + bm * 256 + tid) * (size_t)nbn + bn] = s4;
    }
  } else {
    #pragma unroll
    for (int mh = 0; mh < 2; ++mh)
      #pragma unroll
      for (int mi = 0; mi < 4; ++mi)
        #pragma unroll
        for (int nr = 0; nr < NREP; ++nr)
          #pragma unroll
          for (int jj = 0; jj < 4; ++jj) {
            const int row = crow0 + mh * 64 + mi * 16 + jj;
            const int col = ccol0 + nr * 16;
            const float val = acc[mh * 4 + mi][nr][jj];
            const size_t idx = (size_t)row * ldc + col;
            if constexpr (EPI == 0) {
              float vv = val + bias[col];
              if (col < CCH) vv *= scale;
              ((bf16*)C)[(size_t)blockIdx.y * sC + idx] = (bf16)vv;
            } else if constexpr (EPI == 3) {
              ((bf16*)C)[(size_t)blockIdx.y * sC + idx] = (bf16)val;
            } else {  // EPI == 2: PV final output
              float* Cf = (float*)C + (size_t)blockIdx.y * sC;
              const float ri = rinv[(size_t)blockIdx.y * M + row];
              Cf[idx] = val * ri + bias[col] + resid[(size_t)blockIdx.y * sC + idx];
            }
          }
  }
#undef STAGE_A
#undef STAGE_B
#undef LOADA
#undef LOADB
#undef MMA
#undef BARX
#undef PIN
#undef LGKM0
#undef VMW
#undef VMWSS
}

// ---------------------------------------------------------------------------
extern "C" void kernel_launch(void* const* d_in, const int* in_sizes, int n_in,
                              void* d_out, int out_size, void* d_ws, size_t ws_size,
                              hipStream_t stream) {
  const float* x   = (const float*)d_in[0];
  const float* gsc = (const float*)d_in[1];
  const float* gbi = (const float*)d_in[2];
  const float* wq  = (const float*)d_in[3];
  const float* bq  = (const float*)d_in[4];
  const float* wk  = (const float*)d_in[5];
  const float* bk  = (const float*)d_in[6];
  const float* wv  = (const float*)d_in[7];
  const float* bv  = (const float*)d_in[8];
  const float* wo  = (const float*)d_in[9];
  const float* bo  = (const float*)d_in[10];
  float* out = (float*)d_out;
  char* ws = (char*)d_ws;

  const float sscale = 0.044194173824159216f;  // 1/sqrt(512)
  const bool batched = ws_size >= 187311104ULL;

  if (batched) {
    // S_all[134.2M] | qk[33.6M] | vt[16.8M] | wT | bcat/bpv/stats | parts |
    // spart[1M] | rinv
    bf16*  S_all = (bf16*)(ws + 0);
    bf16*  hf    = (bf16*)(ws + 0);             // alias: dead before S written
    bf16*  qk    = (bf16*)(ws + 134217728);
    bf16*  vt    = (bf16*)(ws + 167772160);
    bf16*  wT    = (bf16*)(ws + 184549376);     // wqT | wkT | W'T
    float* bcat  = (float*)(ws + 186122240);
    float* bpv   = (float*)(ws + 186128384);
    float* stats = (float*)(ws + 186130432);
    float* parts = (float*)(ws + 186131456);
    float* spart = (float*)(ws + 186196992);    // 16384 x 16 f32
    float* rinv  = (float*)(ws + 187245568);    // 16384 f32

    gn_partial<<<dim3(64, NB), 256, 0, stream>>>((const float4*)x, parts);
    gn_reduce<<<1, 128, 0, stream>>>(parts, stats);
    gn_apply<<<8192, 256, 0, stream>>>((const float4*)x, stats, gsc, gbi, hf);
    wcast_t<<<dim3(64, 2), 256, 0, stream>>>(wq, wk, bq, bk, wT, bcat);
    prep_w<<<64, 256, 0, stream>>>(wv, wo, bv, bo, wT + 2 * CCH * CCH, bpv);

    // QK proj: [16384,512] @ [1024,512]^T (q scaled). 64x8 = 512 blocks.
    gemm256<128, 0><<<dim3(512, 1), 512, 0, stream>>>(
        hf, 512, 0, wT, 512, 0, qk, 1024, 0, bcat, nullptr, nullptr, nullptr,
        16384, 1024, 512, sscale);
    // V'^T direct: vt[d][tok] = W'^T @ hf^T. M=512, N=16384. 2x128 = 256 blk.
    gemm256<128, 3><<<dim3(256, 1), 512, 0, stream>>>(
        wT + 2 * CCH * CCH, 512, 0, hf, 512, 0, vt, 16384, 0,
        nullptr, nullptr, nullptr, nullptr, 512, 16384, 512, 0.f);
    // scores: exp(q @ k^T) bf16 + row-sum partials. 256 blocks x 4 batches.
    gemm256<256, 1><<<dim3(256, NB), 512, 0, stream>>>(
        qk, 1024, (size_t)NTOK * 1024, qk + 512, 1024, (size_t)NTOK * 1024,
        S_all, NTOK, (size_t)NTOK * NTOK, nullptr, nullptr, spart, nullptr,
        NTOK, NTOK, CCH, 0.f);
    rowsum_inv<<<64, 256, 0, stream>>>(spart, rinv);
    // out = x + (P_unnorm @ V') * rinv + bpv (final, f32). 64 x 4 batches.
    gemm256<128, 2><<<dim3(64, NB), 512, 0, stream>>>(
        S_all, NTOK, (size_t)NTOK * NTOK, vt, 16384, (size_t)NTOK,
        out, CCH, (size_t)NTOK * CCH, bpv, x, nullptr, rinv,
        NTOK, CCH, NTOK, 0.f);
  } else {
    // fallback (per-batch S): S1[33.6M] | qk[33.6M] | vt[16.8M] | wT | extras
    bf16*  S1    = (bf16*)(ws + 0);
    bf16*  hf    = (bf16*)(ws + 0);
    bf16*  qk    = (bf16*)(ws + 33554432);
    bf16*  vt    = (bf16*)(ws + 67108864);
    bf16*  wT    = (bf16*)(ws + 83886080);
    float* bcat  = (float*)(ws + 85458944);
    float* bpv   = (float*)(ws + 85463040);
    float* stats = (float*)(ws + 85465088);
    float* parts = (float*)(ws + 85466112);
    float* spart = (float*)(ws + 85531648);    // 4096 x 16 f32
    float* rinv  = (float*)(ws + 85793792);    // 4096 f32

    gn_partial<<<dim3(64, NB), 256, 0, stream>>>((const float4*)x, parts);
    gn_reduce<<<1, 128, 0, stream>>>(parts, stats);
    gn_apply<<<8192, 256, 0, stream>>>((const float4*)x, stats, gsc, gbi, hf);
    wcast_t<<<dim3(64, 2), 256, 0, stream>>>(wq, wk, bq, bk, wT, bcat);
    prep_w<<<64, 256, 0, stream>>>(wv, wo, bv, bo, wT + 2 * CCH * CCH, bpv);
    gemm256<128, 0><<<dim3(512, 1), 512, 0, stream>>>(
        hf, 512, 0, wT, 512, 0, qk, 1024, 0, bcat, nullptr, nullptr, nullptr,
        16384, 1024, 512, sscale);
    gemm256<128, 3><<<dim3(256, 1), 512, 0, stream>>>(
        wT + 2 * CCH * CCH, 512, 0, hf, 512, 0, vt, 16384, 0,
        nullptr, nullptr, nullptr, nullptr, 512, 16384, 512, 0.f);
    for (int b = 0; b < NB; ++b) {
      const bf16* qb = qk + (size_t)b * NTOK * 1024;
      gemm256<256, 1><<<dim3(256, 1), 512, 0, stream>>>(
          qb, 1024, 0, qb + 512, 1024, 0, S1, NTOK, 0, nullptr, nullptr,
          spart, nullptr, NTOK, NTOK, CCH, 0.f);
      rowsum_inv<<<16, 256, 0, stream>>>(spart, rinv);
      gemm256<128, 2><<<dim3(64, 1), 512, 0, stream>>>(
          S1, NTOK, 0, vt + (size_t)b * NTOK, 16384, 0,
          out + (size_t)b * NTOK * CCH, CCH, 0, bpv, x + (size_t)b * NTOK * CCH,
          nullptr, rinv, NTOK, CCH, NTOK, 0.f);
    }
  }
}